// Round 4
// baseline (739.109 us; speedup 1.0000x reference)
//
#include <hip/hip_runtime.h>
#include <hip/hip_bf16.h>

// ---------------------------------------------------------------------------
// MCT tracklet-affinity pipeline. fp32 in/out, bf16 MFMA internally.
//   g    = f - relu(f @ Wc1^T + bc1)             [192,4096] fp32 in ws
//   dist = |g_i - g_j| for upper-tri rows        [R,4096] bf16, materialized
//   h1   = relu(dist @ W1^T + b1)                [R,2048] bf16
//   h2   = relu(h1 @ W2^T + b2)                  [R,1024]  (overlays dist)
//   logit[r] += relu(h2 @ W3^T + b3) . Ws        (k_gemm3: fused L3+head dot,
//                                                 fp32 atomicAdd per row)
//   A[i,j]=A[j,i]=sigmoid(logit + bs)            (k_sig, once at end)
// Round-13 == round-12 resubmit (container failed twice; audit found no
// device-hazard in the diff: xcd_map is bijective for all launched grids,
// all addresses in-range, no sync/memory changes).
// Round-12: column-band XCD swizzle (T1) on k_gemm_relu / k_gemm3.
// Diagnosis: L1-big FETCH_SIZE = 688 MB vs ~117 MB ideal — B (W1b) re-fetch
// because per-XCD B residency depended on the UNDEFINED workgroup->XCD
// mapping. Remap so XCD x (= bid&7) owns a contiguous column band: B per
// XCD = 2 col-tiles = 2 MB, pinned in 4 MB L2 under %8 mapping; under a
// chunked mapping the remapped order is also a column band — robust both
// ways. All GEMM grids are multiples of 8 (rows are x128). Chunk ladder
// stays at measured-best 14336.
// GEMM core unchanged: 16x16x32 MFMA, XOR-swizzled LDS (0 bank conflicts),
// global_load_lds width-16 staging, 2-barrier K-loop.
// ---------------------------------------------------------------------------

typedef unsigned short u16;
typedef __attribute__((ext_vector_type(8))) short    bf16x8;
typedef __attribute__((ext_vector_type(8))) unsigned short u16x8;
typedef __attribute__((ext_vector_type(4))) float    f32x4;

#define MFMA16(a, b, c) __builtin_amdgcn_mfma_f32_16x16x32_bf16((a), (b), (c), 0, 0, 0)

#define NTRK 192
#define TRI  18528         /* 192*193/2 upper-tri rows incl diagonal */
#define TRIP 18688         /* padded to 146*128 */

__device__ __forceinline__ unsigned int pkbf(float lo, float hi) {
    __hip_bfloat162 h2 = __float22bfloat162_rn(make_float2(lo, hi));
    return *reinterpret_cast<unsigned int*>(&h2);
}
__device__ __forceinline__ void gll16(void* lds_uniform, const void* gsrc) {
    __builtin_amdgcn_global_load_lds(
        (__attribute__((address_space(1))) void*)(gsrc),
        (__attribute__((address_space(3))) void*)(lds_uniform),
        16, 0, 0);
}
// triangle row r -> (i,j), i<=j. T(i) = i*(385-i)/2. Clamped for padding rows.
__device__ __forceinline__ void tri_decode(int r, int& oi, int& oj) {
    double a = 192.5;
    int i = (int)(a - sqrt(a * a - 2.0 * (double)r));
    i = i < 0 ? 0 : (i > 191 ? 191 : i);
    while (i < 191 && (i + 1) * (385 - (i + 1)) / 2 <= r) ++i;
    while (i > 0 && i * (385 - i) / 2 > r) --i;
    int j = i + (r - i * (385 - i) / 2);
    oi = i; oj = j > 191 ? 191 : j;
}
// Column-band XCD swizzle. Work w enumerated column-major (col=w/gy,
// row=w%gy); XCD x (= b&7 under the measured m09 round-robin mapping) owns
// w in [x*q,(x+1)*q), q=nb/8. Requires nb%8==0 (guaranteed: rows are x128).
// Under a contiguous-chunk mapping the remapped order is also a column
// band, so per-XCD B residency holds under either mapping.
__device__ __forceinline__ void xcd_map(int& obx, int& oby) {
    const int gx = gridDim.x, gy = gridDim.y;
    const int b = blockIdx.y * gx + blockIdx.x;
    const int nb = gx * gy;
    const int q = nb >> 3;
    const int w = (b & 7) * q + (b >> 3);
    const int bx = w / gy;
    obx = bx; oby = w - bx * gy;
}

// ---------------------------------------------------------------------------
// All five fp32->bf16 conversions in ONE launch. Segment sizes in f32x4:
// Wc1 4194304 | W1 2097152 | W2 524288 | W3 131072 | f 196608  (sum 7143424)
// ---------------------------------------------------------------------------
#define CVT_N 7143424
__global__ __launch_bounds__(256)
void k_cvt_all(const float* __restrict__ s0, u16* __restrict__ d0,
               const float* __restrict__ s1, u16* __restrict__ d1,
               const float* __restrict__ s2, u16* __restrict__ d2,
               const float* __restrict__ s3, u16* __restrict__ d3,
               const float* __restrict__ s4, u16* __restrict__ d4)
{
    int i = blockIdx.x * 256 + threadIdx.x;
    if (i >= CVT_N) return;
    const float* s; u16* d; int j;
    if      (i < 4194304) { s = s0; d = d0; j = i; }
    else if (i < 6291456) { s = s1; d = d1; j = i - 4194304; }
    else if (i < 6815744) { s = s2; d = d2; j = i - 6291456; }
    else if (i < 6946816) { s = s3; d = d3; j = i - 6815744; }
    else                  { s = s4; d = d4; j = i - 6946816; }
    f32x4 v = ((const f32x4*)s)[j];
    ((uint2*)d)[j] = make_uint2(pkbf(v.x, v.y), pkbf(v.z, v.w));
}

// ---------------------------------------------------------------------------
// cam partials: camp[z][row][col] = (fb @ Wc1b^T) over k in [z*1024,(z+1)*1024)
// M=192,N=4096. BM=64,BN=128,BK=64, split-K=4 via blockIdx.z. grid (3,32,4).
// ---------------------------------------------------------------------------
__global__ __launch_bounds__(256, 2)
void k_cam(const u16* __restrict__ fb, const u16* __restrict__ Wc1b,
           float* __restrict__ camp)
{
    __shared__ __align__(16) u16 As[64 * 64];
    __shared__ __align__(16) u16 Bs[128 * 64];
    const int t = threadIdx.x, l = t & 63, w = t >> 6;
    const int m0 = blockIdx.x * 64, n0 = blockIdx.y * 128;
    const int kbeg = blockIdx.z * 1024, kend = kbeg + 1024;
    const int lr8 = l >> 3;
    const int lc8 = (l & 7) ^ lr8;
    const u16* Ab = fb   + (size_t)(m0 + w * 16 + lr8) * 4096 + lc8 * 8;
    const u16* Bb = Wc1b + (size_t)(n0 + w * 32 + lr8) * 4096 + lc8 * 8;
    f32x4 acc[2][4] = {};
    const int wr = (w >> 1) * 32, wc = (w & 1) * 64;
    const int lrow = l & 15, lq = l >> 4, s = lrow & 7;

    for (int k0 = kbeg; k0 < kend; k0 += 64) {
        __syncthreads();
#pragma unroll
        for (int q = 0; q < 2; ++q)
            gll16(&As[(w * 16 + q * 8) * 64], Ab + (size_t)q * 8 * 4096 + k0);
#pragma unroll
        for (int q = 0; q < 4; ++q)
            gll16(&Bs[(w * 32 + q * 8) * 64], Bb + (size_t)q * 8 * 4096 + k0);
        __syncthreads();
#pragma unroll
        for (int kk8 = 0; kk8 < 8; kk8 += 4) {
            const int co = ((kk8 + lq) ^ s) * 8;
            bf16x8 af[2], bfr[4];
#pragma unroll
            for (int mi = 0; mi < 2; ++mi)
                af[mi] = *(const bf16x8*)&As[(wr + mi * 16 + lrow) * 64 + co];
#pragma unroll
            for (int ni = 0; ni < 4; ++ni)
                bfr[ni] = *(const bf16x8*)&Bs[(wc + ni * 16 + lrow) * 64 + co];
#pragma unroll
            for (int mi = 0; mi < 2; ++mi)
#pragma unroll
                for (int ni = 0; ni < 4; ++ni)
                    acc[mi][ni] = MFMA16(af[mi], bfr[ni], acc[mi][ni]);
        }
    }
    float* cz = camp + (size_t)blockIdx.z * 192 * 4096;
    const int rq = (l >> 4) * 4;
#pragma unroll
    for (int ni = 0; ni < 4; ++ni) {
        const int col = n0 + wc + ni * 16 + lrow;
#pragma unroll
        for (int mi = 0; mi < 2; ++mi) {
            const int rbase = m0 + wr + mi * 16 + rq;
#pragma unroll
            for (int v = 0; v < 4; ++v)
                cz[(size_t)(rbase + v) * 4096 + col] = acc[mi][ni][v];
        }
    }
}

// ---------------------------------------------------------------------------
// g = f - relu(sum_z camp[z] + bc1). 196608 f32x4 groups, grid 768.
// ---------------------------------------------------------------------------
__global__ __launch_bounds__(256)
void k_gfin(const float* __restrict__ camp, const float* __restrict__ bc1,
            const float* __restrict__ f, float* __restrict__ g)
{
    const int i = blockIdx.x * 256 + threadIdx.x;       // < 196608
    const int col4 = (i * 4) & 4095;
    f32x4 p0 = ((const f32x4*)camp)[i];
    f32x4 p1 = ((const f32x4*)(camp + 786432))[i];
    f32x4 p2 = ((const f32x4*)(camp + 1572864))[i];
    f32x4 p3 = ((const f32x4*)(camp + 2359296))[i];
    f32x4 b = *(const f32x4*)(bc1 + col4);
    f32x4 fv = ((const f32x4*)f)[i];
    f32x4 r;
    r.x = fv.x - fmaxf(p0.x + p1.x + p2.x + p3.x + b.x, 0.0f);
    r.y = fv.y - fmaxf(p0.y + p1.y + p2.y + p3.y + b.y, 0.0f);
    r.z = fv.z - fmaxf(p0.z + p1.z + p2.z + p3.z + b.z, 0.0f);
    r.w = fv.w - fmaxf(p0.w + p1.w + p2.w + p3.w + b.w, 0.0f);
    ((f32x4*)g)[i] = r;
}

// ---------------------------------------------------------------------------
// dist[r, :] = bf16(|g_i - g_j|). One 16B chunk per thread. grid (2, rows).
// ---------------------------------------------------------------------------
__global__ __launch_bounds__(256)
void k_distgen(const float* __restrict__ g, u16* __restrict__ dist, int row0)
{
    const int r = blockIdx.y;
    const int c = blockIdx.x * 256 + threadIdx.x;       // chunk 0..511
    int pi, pj; tri_decode(row0 + r, pi, pj);
    const float* gi = g + (size_t)pi * 4096 + c * 8;
    const float* gj = g + (size_t)pj * 4096 + c * 8;
    f32x4 a0 = ((const f32x4*)gi)[0], a1 = ((const f32x4*)gi)[1];
    f32x4 b0 = ((const f32x4*)gj)[0], b1 = ((const f32x4*)gj)[1];
    uint4 o;
    o.x = pkbf(fabsf(b0.x - a0.x), fabsf(b0.y - a0.y));
    o.y = pkbf(fabsf(b0.z - a0.z), fabsf(b0.w - a0.w));
    o.z = pkbf(fabsf(b1.x - a1.x), fabsf(b1.y - a1.y));
    o.w = pkbf(fabsf(b1.z - a1.z), fabsf(b1.w - a1.w));
    *reinterpret_cast<uint4*>(dist + (size_t)r * 4096 + c * 8) = o;
}

// ---------------------------------------------------------------------------
// C = relu(A @ B^T + bias), bf16, 16x16x32 MFMA. BM=BN=128, BK=64, 256 thr,
// wave tile 64x64. Work order: column-major with XCD column-band swizzle.
// XOR-swizzled LDS: stage chunk (l&7)^(l>>3), read chunk (ck)^(row&7).
// ---------------------------------------------------------------------------
__global__ __launch_bounds__(256, 2)
void k_gemm_relu(const u16* __restrict__ A, const u16* __restrict__ B,
                 const float* __restrict__ bias, u16* __restrict__ C,
                 int N, int K)
{
    __shared__ __align__(16) u16 As[128 * 64];
    __shared__ __align__(16) u16 Bs[128 * 64];
    const int t = threadIdx.x, l = t & 63, w = t >> 6;
    int bx, by; xcd_map(bx, by);
    const int m0 = by * 128, n0 = bx * 128;
    const int lr8 = l >> 3;
    const int lc8 = (l & 7) ^ lr8;
    const u16* Ab = A + (size_t)(m0 + w * 32 + lr8) * K + lc8 * 8;
    const u16* Bb = B + (size_t)(n0 + w * 32 + lr8) * K + lc8 * 8;
    f32x4 acc[4][4] = {};
    const int wr = (w >> 1) * 64, wc = (w & 1) * 64;
    const int lrow = l & 15, lq = l >> 4, s = lrow & 7;

    for (int k0 = 0; k0 < K; k0 += 64) {
        __syncthreads();
#pragma unroll
        for (int q = 0; q < 4; ++q) {
            gll16(&As[(w * 32 + q * 8) * 64], Ab + (size_t)q * 8 * K + k0);
            gll16(&Bs[(w * 32 + q * 8) * 64], Bb + (size_t)q * 8 * K + k0);
        }
        __syncthreads();
#pragma unroll
        for (int kk8 = 0; kk8 < 8; kk8 += 4) {
            const int co = ((kk8 + lq) ^ s) * 8;
            bf16x8 af[4], bfr[4];
#pragma unroll
            for (int mi = 0; mi < 4; ++mi)
                af[mi] = *(const bf16x8*)&As[(wr + mi * 16 + lrow) * 64 + co];
#pragma unroll
            for (int ni = 0; ni < 4; ++ni)
                bfr[ni] = *(const bf16x8*)&Bs[(wc + ni * 16 + lrow) * 64 + co];
#pragma unroll
            for (int mi = 0; mi < 4; ++mi)
#pragma unroll
                for (int ni = 0; ni < 4; ++ni)
                    acc[mi][ni] = MFMA16(af[mi], bfr[ni], acc[mi][ni]);
        }
    }
    const int rq = (l >> 4) * 4;
#pragma unroll
    for (int ni = 0; ni < 4; ++ni) {
        const int col = n0 + wc + ni * 16 + lrow;
        const float bv = bias[col];
#pragma unroll
        for (int mi = 0; mi < 4; ++mi) {
            const int rbase = m0 + wr + mi * 16 + rq;
#pragma unroll
            for (int v = 0; v < 4; ++v) {
                float x = fmaxf(acc[mi][ni][v] + bv, 0.0f);
                C[(size_t)(rbase + v) * N + col] = (u16)(pkbf(x, 0.0f) & 0xFFFF);
            }
        }
    }
}

// ---------------------------------------------------------------------------
// Fused L3+head: logit[r0+row] += sum_col relu(h2@W3^T + b3)[row,col]*Ws[col].
// Same GEMM core (N=512, K=1024, grid (4, rows/128)), column-band swizzle.
// Epilogue: per (mi,v) row-slot, dot partial over this lane's 4 cols,
// butterfly-reduce across the 16 lrow lanes, one fp32 atomicAdd per row-slot.
// ---------------------------------------------------------------------------
__global__ __launch_bounds__(256, 2)
void k_gemm3(const u16* __restrict__ A, const u16* __restrict__ B,
             const float* __restrict__ bias, const float* __restrict__ Wsv,
             float* __restrict__ logit, int r0)
{
    const int N = 512, K = 1024;
    __shared__ __align__(16) u16 As[128 * 64];
    __shared__ __align__(16) u16 Bs[128 * 64];
    const int t = threadIdx.x, l = t & 63, w = t >> 6;
    int bx, by; xcd_map(bx, by);
    const int m0 = by * 128, n0 = bx * 128;
    const int lr8 = l >> 3;
    const int lc8 = (l & 7) ^ lr8;
    const u16* Ab = A + (size_t)(m0 + w * 32 + lr8) * K + lc8 * 8;
    const u16* Bb = B + (size_t)(n0 + w * 32 + lr8) * K + lc8 * 8;
    f32x4 acc[4][4] = {};
    const int wr = (w >> 1) * 64, wc = (w & 1) * 64;
    const int lrow = l & 15, lq = l >> 4, s = lrow & 7;

    for (int k0 = 0; k0 < K; k0 += 64) {
        __syncthreads();
#pragma unroll
        for (int q = 0; q < 4; ++q) {
            gll16(&As[(w * 32 + q * 8) * 64], Ab + (size_t)q * 8 * K + k0);
            gll16(&Bs[(w * 32 + q * 8) * 64], Bb + (size_t)q * 8 * K + k0);
        }
        __syncthreads();
#pragma unroll
        for (int kk8 = 0; kk8 < 8; kk8 += 4) {
            const int co = ((kk8 + lq) ^ s) * 8;
            bf16x8 af[4], bfr[4];
#pragma unroll
            for (int mi = 0; mi < 4; ++mi)
                af[mi] = *(const bf16x8*)&As[(wr + mi * 16 + lrow) * 64 + co];
#pragma unroll
            for (int ni = 0; ni < 4; ++ni)
                bfr[ni] = *(const bf16x8*)&Bs[(wc + ni * 16 + lrow) * 64 + co];
#pragma unroll
            for (int mi = 0; mi < 4; ++mi)
#pragma unroll
                for (int ni = 0; ni < 4; ++ni)
                    acc[mi][ni] = MFMA16(af[mi], bfr[ni], acc[mi][ni]);
        }
    }
    const int rq = (l >> 4) * 4;
    float wv[4], bv[4];
#pragma unroll
    for (int ni = 0; ni < 4; ++ni) {
        const int col = n0 + wc + ni * 16 + lrow;
        wv[ni] = Wsv[col];
        bv[ni] = bias[col];
    }
#pragma unroll
    for (int mi = 0; mi < 4; ++mi) {
#pragma unroll
        for (int v = 0; v < 4; ++v) {
            float p = 0.0f;
#pragma unroll
            for (int ni = 0; ni < 4; ++ni)
                p += fmaxf(acc[mi][ni][v] + bv[ni], 0.0f) * wv[ni];
            p += __shfl_xor(p, 1, 64);
            p += __shfl_xor(p, 2, 64);
            p += __shfl_xor(p, 4, 64);
            p += __shfl_xor(p, 8, 64);
            if (lrow == 0)
                atomicAdd(&logit[r0 + m0 + wr + mi * 16 + rq + v], p);
        }
    }
}

// ---------------------------------------------------------------------------
// out[i,j] = out[j,i] = sigmoid(logit[r] + bs). One thread per tri-row.
// ---------------------------------------------------------------------------
__global__ __launch_bounds__(256)
void k_sig(const float* __restrict__ logit, const float* __restrict__ bsv,
           float* __restrict__ out)
{
    const int r = blockIdx.x * 256 + threadIdx.x;
    if (r >= TRI) return;
    int pi, pj; tri_decode(r, pi, pj);
    float v = 1.0f / (1.0f + __expf(-(logit[r] + bsv[0])));
    out[pi * NTRK + pj] = v;
    out[pj * NTRK + pi] = v;
}

// ---------------------------------------------------------------------------
extern "C" void kernel_launch(void* const* d_in, const int* in_sizes, int n_in,
                              void* d_out, int out_size, void* d_ws, size_t ws_size,
                              hipStream_t stream)
{
    const float* f   = (const float*)d_in[0];
    const float* Wc1 = (const float*)d_in[1];
    const float* bc1 = (const float*)d_in[2];
    const float* W1  = (const float*)d_in[3];
    const float* b1  = (const float*)d_in[4];
    const float* W2  = (const float*)d_in[5];
    const float* b2  = (const float*)d_in[6];
    const float* W3  = (const float*)d_in[7];
    const float* b3  = (const float*)d_in[8];
    const float* Wsv = (const float*)d_in[9];
    const float* bsv = (const float*)d_in[10];
    float* out = (float*)d_out;

    // ---- workspace layout ----
    // persistent: W1b 16M | W2b 4M | W3b 1M | fb 1.5M | g 3M | logit 75K
    // overlay region at chunkbase:
    //   phase A: Wc1b (32M) + camp (12M)   [dead before chunk loop]
    //   phase B: dist (8192R) + h1 (4096R); h2 (2048R) overlays dist.
    char* wsb = (char*)d_ws;
    size_t off = 0;
    u16*   W1b   = (u16*)(wsb + off);  off += (size_t)2048 * 4096 * 2;
    u16*   W2b   = (u16*)(wsb + off);  off += (size_t)1024 * 2048 * 2;
    u16*   W3b   = (u16*)(wsb + off);  off += (size_t)512  * 1024 * 2;
    u16*   fb    = (u16*)(wsb + off);  off += (size_t)192  * 4096 * 2;
    float* g     = (float*)(wsb + off); off += (size_t)192 * 4096 * 4;
    float* logit = (float*)(wsb + off); off += (size_t)TRIP * 4;
    const size_t chunkbase = off;
    u16*   Wc1b = (u16*)(wsb + chunkbase);
    float* camp = (float*)(wsb + chunkbase + (size_t)4096 * 4096 * 2);
    const size_t phaseA = (size_t)4096 * 4096 * 2 + (size_t)4 * 192 * 4096 * 4;

    // measured-best asymmetric ladder (round-9); all resulting grids are
    // multiples of 8 blocks (rows x128) as required by xcd_map.
    const int Rcand[6] = {18688, 14336, 9344, 4736, 2432, 1280};
    int R = 128;
    for (int c = 0; c < 6; ++c) {
        size_t chunk = (size_t)Rcand[c] * 12288;
        if (chunk < phaseA) chunk = phaseA;
        if (chunkbase + chunk <= ws_size) { R = Rcand[c]; break; }
    }
    u16* dist = (u16*)(wsb + chunkbase);
    u16* h1 = dist + (size_t)R * 4096;
    u16* h2 = dist;                       // overlays dist (dead after L1)

    hipMemsetAsync(logit, 0, (size_t)TRIP * 4, stream);
    k_cvt_all<<<(CVT_N + 255) / 256, 256, 0, stream>>>(
        Wc1, Wc1b, W1, W1b, W2, W2b, W3, W3b, f, fb);
    k_cam<<<dim3(3, 32, 4), 256, 0, stream>>>(fb, Wc1b, camp);
    k_gfin<<<768, 256, 0, stream>>>(camp, bc1, f, g);

    for (int r0 = 0; r0 < TRI; r0 += R) {
        int rows = TRIP - r0; if (rows > R) rows = R;   // mult of 128
        k_distgen<<<dim3(2, rows), 256, 0, stream>>>(g, dist, r0);
        k_gemm_relu<<<dim3(16, rows / 128), 256, 0, stream>>>(dist, W1b, b1, h1, 2048, 4096);
        k_gemm_relu<<<dim3(8,  rows / 128), 256, 0, stream>>>(h1, W2b, b2, h2, 1024, 2048);
        k_gemm3<<<dim3(4, rows / 128), 256, 0, stream>>>(h2, W3b, b3, Wsv, logit, r0);
    }
    k_sig<<<(TRI + 255) / 256, 256, 0, stream>>>(logit, bsv, out);
}

// Round 5
// 713.580 us; speedup vs baseline: 1.0358x; 1.0358x over previous
//
#include <hip/hip_runtime.h>
#include <hip/hip_bf16.h>

// ---------------------------------------------------------------------------
// MCT tracklet-affinity pipeline. fp32 in/out, bf16 MFMA internally.
//   g    = f - relu(f @ Wc1^T + bc1)             [192,4096] fp32 in ws
//   dist = |g_i - g_j| for upper-tri rows        [R,4096] bf16, materialized
//   h1   = relu(dist @ W1^T + b1)                [R,2048] bf16
//   h2   = relu(h1 @ W2^T + b2)                  [R,1024]  (overlays dist)
//   logit[r] += relu(h2 @ W3^T + b3) . Ws        (k_gemm3: fused L3+head dot)
//   A[i,j]=A[j,i]=sigmoid(logit + bs)            (k_sig, once at end)
// Round-14: (a) REVERT round-12 XCD column-band swizzle — it RAISED L2-miss
// traffic 688->1237 MB / 300->385 us: FETCH_SIZE is L2-miss traffic served
// by L3 (chunk fits Infinity Cache), and the default row-major %8 order
// already achieves the per-XCD-L2 structural optimum (~0.4 MB/tile-op);
// banding destroyed A row-tile reuse. (b) k_gemm_relu inner core switched
// 16x16x32 -> 32x32x16 MFMA (same 64x64 wave tile = 2x2 of 32x32): measured
// ubench 2382 vs 2075 TF = +17% FLOP/cycle on the MFMA pipe. Operand maps:
// A/B row|col = l&31, k = (l>>5)*8+e; C/D col=lane&31,
// row=(reg&3)+8*(reg>>2)+4*(lane>>5) [learn_hip m74/m101 HW-verified].
// XOR-swizzle read chunk = (kk*2+(l>>5))^(row&7): bijective per 8-lane
// phase group -> conflict-free (same structure as the proven 16x16 reads).
// k_cam / k_gemm3 keep the 16x16 core (gemm3 epilogue depends on it).
// Chunk ladder: measured-best {14336, 4352} asymmetric split.
// ---------------------------------------------------------------------------

typedef unsigned short u16;
typedef __attribute__((ext_vector_type(8))) short    bf16x8;
typedef __attribute__((ext_vector_type(8))) unsigned short u16x8;
typedef __attribute__((ext_vector_type(4))) float    f32x4;
typedef __attribute__((ext_vector_type(16))) float   f32x16;

#define MFMA16(a, b, c) __builtin_amdgcn_mfma_f32_16x16x32_bf16((a), (b), (c), 0, 0, 0)
#define MFMA32(a, b, c) __builtin_amdgcn_mfma_f32_32x32x16_bf16((a), (b), (c), 0, 0, 0)

#define NTRK 192
#define TRI  18528         /* 192*193/2 upper-tri rows incl diagonal */
#define TRIP 18688         /* padded to 146*128 */

__device__ __forceinline__ unsigned int pkbf(float lo, float hi) {
    __hip_bfloat162 h2 = __float22bfloat162_rn(make_float2(lo, hi));
    return *reinterpret_cast<unsigned int*>(&h2);
}
__device__ __forceinline__ void gll16(void* lds_uniform, const void* gsrc) {
    __builtin_amdgcn_global_load_lds(
        (__attribute__((address_space(1))) void*)(gsrc),
        (__attribute__((address_space(3))) void*)(lds_uniform),
        16, 0, 0);
}
// triangle row r -> (i,j), i<=j. T(i) = i*(385-i)/2. Clamped for padding rows.
__device__ __forceinline__ void tri_decode(int r, int& oi, int& oj) {
    double a = 192.5;
    int i = (int)(a - sqrt(a * a - 2.0 * (double)r));
    i = i < 0 ? 0 : (i > 191 ? 191 : i);
    while (i < 191 && (i + 1) * (385 - (i + 1)) / 2 <= r) ++i;
    while (i > 0 && i * (385 - i) / 2 > r) --i;
    int j = i + (r - i * (385 - i) / 2);
    oi = i; oj = j > 191 ? 191 : j;
}

// ---------------------------------------------------------------------------
// All five fp32->bf16 conversions in ONE launch. Segment sizes in f32x4:
// Wc1 4194304 | W1 2097152 | W2 524288 | W3 131072 | f 196608  (sum 7143424)
// ---------------------------------------------------------------------------
#define CVT_N 7143424
__global__ __launch_bounds__(256)
void k_cvt_all(const float* __restrict__ s0, u16* __restrict__ d0,
               const float* __restrict__ s1, u16* __restrict__ d1,
               const float* __restrict__ s2, u16* __restrict__ d2,
               const float* __restrict__ s3, u16* __restrict__ d3,
               const float* __restrict__ s4, u16* __restrict__ d4)
{
    int i = blockIdx.x * 256 + threadIdx.x;
    if (i >= CVT_N) return;
    const float* s; u16* d; int j;
    if      (i < 4194304) { s = s0; d = d0; j = i; }
    else if (i < 6291456) { s = s1; d = d1; j = i - 4194304; }
    else if (i < 6815744) { s = s2; d = d2; j = i - 6291456; }
    else if (i < 6946816) { s = s3; d = d3; j = i - 6815744; }
    else                  { s = s4; d = d4; j = i - 6946816; }
    f32x4 v = ((const f32x4*)s)[j];
    ((uint2*)d)[j] = make_uint2(pkbf(v.x, v.y), pkbf(v.z, v.w));
}

// ---------------------------------------------------------------------------
// cam partials: camp[z][row][col] = (fb @ Wc1b^T) over k in [z*1024,(z+1)*1024)
// M=192,N=4096. BM=64,BN=128,BK=64, split-K=4 via blockIdx.z. grid (3,32,4).
// ---------------------------------------------------------------------------
__global__ __launch_bounds__(256, 2)
void k_cam(const u16* __restrict__ fb, const u16* __restrict__ Wc1b,
           float* __restrict__ camp)
{
    __shared__ __align__(16) u16 As[64 * 64];
    __shared__ __align__(16) u16 Bs[128 * 64];
    const int t = threadIdx.x, l = t & 63, w = t >> 6;
    const int m0 = blockIdx.x * 64, n0 = blockIdx.y * 128;
    const int kbeg = blockIdx.z * 1024, kend = kbeg + 1024;
    const int lr8 = l >> 3;
    const int lc8 = (l & 7) ^ lr8;
    const u16* Ab = fb   + (size_t)(m0 + w * 16 + lr8) * 4096 + lc8 * 8;
    const u16* Bb = Wc1b + (size_t)(n0 + w * 32 + lr8) * 4096 + lc8 * 8;
    f32x4 acc[2][4] = {};
    const int wr = (w >> 1) * 32, wc = (w & 1) * 64;
    const int lrow = l & 15, lq = l >> 4, s = lrow & 7;

    for (int k0 = kbeg; k0 < kend; k0 += 64) {
        __syncthreads();
#pragma unroll
        for (int q = 0; q < 2; ++q)
            gll16(&As[(w * 16 + q * 8) * 64], Ab + (size_t)q * 8 * 4096 + k0);
#pragma unroll
        for (int q = 0; q < 4; ++q)
            gll16(&Bs[(w * 32 + q * 8) * 64], Bb + (size_t)q * 8 * 4096 + k0);
        __syncthreads();
#pragma unroll
        for (int kk8 = 0; kk8 < 8; kk8 += 4) {
            const int co = ((kk8 + lq) ^ s) * 8;
            bf16x8 af[2], bfr[4];
#pragma unroll
            for (int mi = 0; mi < 2; ++mi)
                af[mi] = *(const bf16x8*)&As[(wr + mi * 16 + lrow) * 64 + co];
#pragma unroll
            for (int ni = 0; ni < 4; ++ni)
                bfr[ni] = *(const bf16x8*)&Bs[(wc + ni * 16 + lrow) * 64 + co];
#pragma unroll
            for (int mi = 0; mi < 2; ++mi)
#pragma unroll
                for (int ni = 0; ni < 4; ++ni)
                    acc[mi][ni] = MFMA16(af[mi], bfr[ni], acc[mi][ni]);
        }
    }
    float* cz = camp + (size_t)blockIdx.z * 192 * 4096;
    const int rq = (l >> 4) * 4;
#pragma unroll
    for (int ni = 0; ni < 4; ++ni) {
        const int col = n0 + wc + ni * 16 + lrow;
#pragma unroll
        for (int mi = 0; mi < 2; ++mi) {
            const int rbase = m0 + wr + mi * 16 + rq;
#pragma unroll
            for (int v = 0; v < 4; ++v)
                cz[(size_t)(rbase + v) * 4096 + col] = acc[mi][ni][v];
        }
    }
}

// ---------------------------------------------------------------------------
// g = f - relu(sum_z camp[z] + bc1). 196608 f32x4 groups, grid 768.
// ---------------------------------------------------------------------------
__global__ __launch_bounds__(256)
void k_gfin(const float* __restrict__ camp, const float* __restrict__ bc1,
            const float* __restrict__ f, float* __restrict__ g)
{
    const int i = blockIdx.x * 256 + threadIdx.x;       // < 196608
    const int col4 = (i * 4) & 4095;
    f32x4 p0 = ((const f32x4*)camp)[i];
    f32x4 p1 = ((const f32x4*)(camp + 786432))[i];
    f32x4 p2 = ((const f32x4*)(camp + 1572864))[i];
    f32x4 p3 = ((const f32x4*)(camp + 2359296))[i];
    f32x4 b = *(const f32x4*)(bc1 + col4);
    f32x4 fv = ((const f32x4*)f)[i];
    f32x4 r;
    r.x = fv.x - fmaxf(p0.x + p1.x + p2.x + p3.x + b.x, 0.0f);
    r.y = fv.y - fmaxf(p0.y + p1.y + p2.y + p3.y + b.y, 0.0f);
    r.z = fv.z - fmaxf(p0.z + p1.z + p2.z + p3.z + b.z, 0.0f);
    r.w = fv.w - fmaxf(p0.w + p1.w + p2.w + p3.w + b.w, 0.0f);
    ((f32x4*)g)[i] = r;
}

// ---------------------------------------------------------------------------
// dist[r, :] = bf16(|g_i - g_j|). One 16B chunk per thread. grid (2, rows).
// ---------------------------------------------------------------------------
__global__ __launch_bounds__(256)
void k_distgen(const float* __restrict__ g, u16* __restrict__ dist, int row0)
{
    const int r = blockIdx.y;
    const int c = blockIdx.x * 256 + threadIdx.x;       // chunk 0..511
    int pi, pj; tri_decode(row0 + r, pi, pj);
    const float* gi = g + (size_t)pi * 4096 + c * 8;
    const float* gj = g + (size_t)pj * 4096 + c * 8;
    f32x4 a0 = ((const f32x4*)gi)[0], a1 = ((const f32x4*)gi)[1];
    f32x4 b0 = ((const f32x4*)gj)[0], b1 = ((const f32x4*)gj)[1];
    uint4 o;
    o.x = pkbf(fabsf(b0.x - a0.x), fabsf(b0.y - a0.y));
    o.y = pkbf(fabsf(b0.z - a0.z), fabsf(b0.w - a0.w));
    o.z = pkbf(fabsf(b1.x - a1.x), fabsf(b1.y - a1.y));
    o.w = pkbf(fabsf(b1.z - a1.z), fabsf(b1.w - a1.w));
    *reinterpret_cast<uint4*>(dist + (size_t)r * 4096 + c * 8) = o;
}

// ---------------------------------------------------------------------------
// C = relu(A @ B^T + bias), bf16, 32x32x16 MFMA. BM=BN=128, BK=64, 256 thr,
// wave tile 64x64 = 2x2 of 32x32. grid (N/128, M/128): x = COLUMN tile.
// LDS staging identical to before (XOR pre-swizzled global source, linear
// dest). Read: row|col = l&31, global chunk g = kk*2 + (l>>5), LDS chunk
// p = g ^ (row&7) — bijective on each 8-lane phase group => conflict-free.
// C/D map: col = lane&31, row = (reg&3) + 8*(reg>>2) + 4*(lane>>5).
// ---------------------------------------------------------------------------
__global__ __launch_bounds__(256, 2)
void k_gemm_relu(const u16* __restrict__ A, const u16* __restrict__ B,
                 const float* __restrict__ bias, u16* __restrict__ C,
                 int N, int K)
{
    __shared__ __align__(16) u16 As[128 * 64];
    __shared__ __align__(16) u16 Bs[128 * 64];
    const int t = threadIdx.x, l = t & 63, w = t >> 6;
    const int m0 = blockIdx.y * 128, n0 = blockIdx.x * 128;   // x = column!
    const int lr8 = l >> 3;
    const int lc8 = (l & 7) ^ lr8;
    const u16* Ab = A + (size_t)(m0 + w * 32 + lr8) * K + lc8 * 8;
    const u16* Bb = B + (size_t)(n0 + w * 32 + lr8) * K + lc8 * 8;
    f32x16 acc[2][2] = {};
    const int wr = (w >> 1) * 64, wc = (w & 1) * 64;
    const int l31 = l & 31, kq = l >> 5, s = l31 & 7;

    for (int k0 = 0; k0 < K; k0 += 64) {
        __syncthreads();
#pragma unroll
        for (int q = 0; q < 4; ++q) {
            gll16(&As[(w * 32 + q * 8) * 64], Ab + (size_t)q * 8 * K + k0);
            gll16(&Bs[(w * 32 + q * 8) * 64], Bb + (size_t)q * 8 * K + k0);
        }
        __syncthreads();
#pragma unroll
        for (int kk = 0; kk < 4; ++kk) {
            const int co = ((kk * 2 + kq) ^ s) * 8;
            bf16x8 af[2], bfr[2];
#pragma unroll
            for (int mi = 0; mi < 2; ++mi)
                af[mi] = *(const bf16x8*)&As[(wr + mi * 32 + l31) * 64 + co];
#pragma unroll
            for (int ni = 0; ni < 2; ++ni)
                bfr[ni] = *(const bf16x8*)&Bs[(wc + ni * 32 + l31) * 64 + co];
#pragma unroll
            for (int mi = 0; mi < 2; ++mi)
#pragma unroll
                for (int ni = 0; ni < 2; ++ni)
                    acc[mi][ni] = MFMA32(af[mi], bfr[ni], acc[mi][ni]);
        }
    }
#pragma unroll
    for (int ni = 0; ni < 2; ++ni) {
        const int col = n0 + wc + ni * 32 + l31;
        const float bv = bias[col];
#pragma unroll
        for (int mi = 0; mi < 2; ++mi) {
            const int rbase = m0 + wr + mi * 32 + 4 * kq;
#pragma unroll
            for (int r16 = 0; r16 < 16; ++r16) {
                const int row = rbase + (r16 & 3) + 8 * (r16 >> 2);
                float x = fmaxf(acc[mi][ni][r16] + bv, 0.0f);
                C[(size_t)row * N + col] = (u16)(pkbf(x, 0.0f) & 0xFFFF);
            }
        }
    }
}

// ---------------------------------------------------------------------------
// Fused L3+head: logit[r0+row] += sum_col relu(h2@W3^T + b3)[row,col]*Ws[col].
// 16x16 GEMM core (N=512, K=1024, grid (4, rows/128)). Epilogue: per (mi,v)
// row-slot, dot partial over this lane's 4 cols, butterfly-reduce across the
// 16 lrow lanes (xor masks 1,2,4,8 stay within the l>>4 quad since row is
// determined by l>>4), one fp32 atomicAdd per row-slot from lane lrow==0.
// ---------------------------------------------------------------------------
__global__ __launch_bounds__(256, 2)
void k_gemm3(const u16* __restrict__ A, const u16* __restrict__ B,
             const float* __restrict__ bias, const float* __restrict__ Wsv,
             float* __restrict__ logit, int r0)
{
    const int N = 512, K = 1024;
    __shared__ __align__(16) u16 As[128 * 64];
    __shared__ __align__(16) u16 Bs[128 * 64];
    const int t = threadIdx.x, l = t & 63, w = t >> 6;
    const int m0 = blockIdx.y * 128, n0 = blockIdx.x * 128;
    const int lr8 = l >> 3;
    const int lc8 = (l & 7) ^ lr8;
    const u16* Ab = A + (size_t)(m0 + w * 32 + lr8) * K + lc8 * 8;
    const u16* Bb = B + (size_t)(n0 + w * 32 + lr8) * K + lc8 * 8;
    f32x4 acc[4][4] = {};
    const int wr = (w >> 1) * 64, wc = (w & 1) * 64;
    const int lrow = l & 15, lq = l >> 4, s = lrow & 7;

    for (int k0 = 0; k0 < K; k0 += 64) {
        __syncthreads();
#pragma unroll
        for (int q = 0; q < 4; ++q) {
            gll16(&As[(w * 32 + q * 8) * 64], Ab + (size_t)q * 8 * K + k0);
            gll16(&Bs[(w * 32 + q * 8) * 64], Bb + (size_t)q * 8 * K + k0);
        }
        __syncthreads();
#pragma unroll
        for (int kk8 = 0; kk8 < 8; kk8 += 4) {
            const int co = ((kk8 + lq) ^ s) * 8;
            bf16x8 af[4], bfr[4];
#pragma unroll
            for (int mi = 0; mi < 4; ++mi)
                af[mi] = *(const bf16x8*)&As[(wr + mi * 16 + lrow) * 64 + co];
#pragma unroll
            for (int ni = 0; ni < 4; ++ni)
                bfr[ni] = *(const bf16x8*)&Bs[(wc + ni * 16 + lrow) * 64 + co];
#pragma unroll
            for (int mi = 0; mi < 4; ++mi)
#pragma unroll
                for (int ni = 0; ni < 4; ++ni)
                    acc[mi][ni] = MFMA16(af[mi], bfr[ni], acc[mi][ni]);
        }
    }
    const int rq = (l >> 4) * 4;
    float wv[4], bv[4];
#pragma unroll
    for (int ni = 0; ni < 4; ++ni) {
        const int col = n0 + wc + ni * 16 + lrow;
        wv[ni] = Wsv[col];
        bv[ni] = bias[col];
    }
#pragma unroll
    for (int mi = 0; mi < 4; ++mi) {
#pragma unroll
        for (int v = 0; v < 4; ++v) {
            float p = 0.0f;
#pragma unroll
            for (int ni = 0; ni < 4; ++ni)
                p += fmaxf(acc[mi][ni][v] + bv[ni], 0.0f) * wv[ni];
            p += __shfl_xor(p, 1, 64);
            p += __shfl_xor(p, 2, 64);
            p += __shfl_xor(p, 4, 64);
            p += __shfl_xor(p, 8, 64);
            if (lrow == 0)
                atomicAdd(&logit[r0 + m0 + wr + mi * 16 + rq + v], p);
        }
    }
}

// ---------------------------------------------------------------------------
// out[i,j] = out[j,i] = sigmoid(logit[r] + bs). One thread per tri-row.
// ---------------------------------------------------------------------------
__global__ __launch_bounds__(256)
void k_sig(const float* __restrict__ logit, const float* __restrict__ bsv,
           float* __restrict__ out)
{
    const int r = blockIdx.x * 256 + threadIdx.x;
    if (r >= TRI) return;
    int pi, pj; tri_decode(r, pi, pj);
    float v = 1.0f / (1.0f + __expf(-(logit[r] + bsv[0])));
    out[pi * NTRK + pj] = v;
    out[pj * NTRK + pi] = v;
}

// ---------------------------------------------------------------------------
extern "C" void kernel_launch(void* const* d_in, const int* in_sizes, int n_in,
                              void* d_out, int out_size, void* d_ws, size_t ws_size,
                              hipStream_t stream)
{
    const float* f   = (const float*)d_in[0];
    const float* Wc1 = (const float*)d_in[1];
    const float* bc1 = (const float*)d_in[2];
    const float* W1  = (const float*)d_in[3];
    const float* b1  = (const float*)d_in[4];
    const float* W2  = (const float*)d_in[5];
    const float* b2  = (const float*)d_in[6];
    const float* W3  = (const float*)d_in[7];
    const float* b3  = (const float*)d_in[8];
    const float* Wsv = (const float*)d_in[9];
    const float* bsv = (const float*)d_in[10];
    float* out = (float*)d_out;

    // ---- workspace layout ----
    // persistent: W1b 16M | W2b 4M | W3b 1M | fb 1.5M | g 3M | logit 75K
    // overlay region at chunkbase:
    //   phase A: Wc1b (32M) + camp (12M)   [dead before chunk loop]
    //   phase B: dist (8192R) + h1 (4096R); h2 (2048R) overlays dist.
    char* wsb = (char*)d_ws;
    size_t off = 0;
    u16*   W1b   = (u16*)(wsb + off);  off += (size_t)2048 * 4096 * 2;
    u16*   W2b   = (u16*)(wsb + off);  off += (size_t)1024 * 2048 * 2;
    u16*   W3b   = (u16*)(wsb + off);  off += (size_t)512  * 1024 * 2;
    u16*   fb    = (u16*)(wsb + off);  off += (size_t)192  * 4096 * 2;
    float* g     = (float*)(wsb + off); off += (size_t)192 * 4096 * 4;
    float* logit = (float*)(wsb + off); off += (size_t)TRIP * 4;
    const size_t chunkbase = off;
    u16*   Wc1b = (u16*)(wsb + chunkbase);
    float* camp = (float*)(wsb + chunkbase + (size_t)4096 * 4096 * 2);
    const size_t phaseA = (size_t)4096 * 4096 * 2 + (size_t)4 * 192 * 4096 * 4;

    // measured-best asymmetric ladder (round-9).
    const int Rcand[6] = {18688, 14336, 9344, 4736, 2432, 1280};
    int R = 128;
    for (int c = 0; c < 6; ++c) {
        size_t chunk = (size_t)Rcand[c] * 12288;
        if (chunk < phaseA) chunk = phaseA;
        if (chunkbase + chunk <= ws_size) { R = Rcand[c]; break; }
    }
    u16* dist = (u16*)(wsb + chunkbase);
    u16* h1 = dist + (size_t)R * 4096;
    u16* h2 = dist;                       // overlays dist (dead after L1)

    hipMemsetAsync(logit, 0, (size_t)TRIP * 4, stream);
    k_cvt_all<<<(CVT_N + 255) / 256, 256, 0, stream>>>(
        Wc1, Wc1b, W1, W1b, W2, W2b, W3, W3b, f, fb);
    k_cam<<<dim3(3, 32, 4), 256, 0, stream>>>(fb, Wc1b, camp);
    k_gfin<<<768, 256, 0, stream>>>(camp, bc1, f, g);

    for (int r0 = 0; r0 < TRI; r0 += R) {
        int rows = TRIP - r0; if (rows > R) rows = R;   // mult of 128
        k_distgen<<<dim3(2, rows), 256, 0, stream>>>(g, dist, r0);
        k_gemm_relu<<<dim3(16, rows / 128), 256, 0, stream>>>(dist, W1b, b1, h1, 2048, 4096);
        k_gemm_relu<<<dim3(8,  rows / 128), 256, 0, stream>>>(h1, W2b, b2, h2, 1024, 2048);
        k_gemm3<<<dim3(4, rows / 128), 256, 0, stream>>>(h2, W3b, b3, Wsv, logit, r0);
    }
    k_sig<<<(TRI + 255) / 256, 256, 0, stream>>>(logit, bsv, out);
}

// Round 6
// 698.210 us; speedup vs baseline: 1.0586x; 1.0220x over previous
//
#include <hip/hip_runtime.h>
#include <hip/hip_bf16.h>

// ---------------------------------------------------------------------------
// MCT tracklet-affinity pipeline. fp32 in/out, bf16 MFMA internally.
//   g    = f - relu(f @ Wc1^T + bc1)             [192,4096] fp32 in ws
//   dist = |g_i - g_j| for upper-tri rows        [R,4096] bf16, materialized
//   h1   = relu(dist @ W1^T + b1)                [R,2048] bf16
//   h2   = relu(h1 @ W2^T + b2)                  [R,1024]  (overlays dist)
//   logit[r] += relu(h2 @ W3^T + b3) . Ws        (k_gemm3: fused L3+head dot)
//   A[i,j]=A[j,i]=sigmoid(logit + bs)            (k_sig, once at end)
// Round-15: (a) revert 32x32 core (bank conflicts 3.8e7, 370us — per-8-lane
// conflict analysis falsified on HW). (b) NEW k_gemm8: 256x256-tile 8-phase
// pipelined GEMM, derived race-free schedule:
//   phases = C-quadrants (r,c); B cols = wn*32 + c*128 so each phase reads
//   ONE B-half. Death windows: A-h after p3, B-h0 after p3, B-h1 after p4.
//   Stages {p1:A(+1,h1), p2:B(+1,h0), p3:B(+1,h1), p4:A(+2,h0)}; every
//   overwrite is barrier-separated from its region's completed reads.
//   vmcnt(4) at p1-end & p4-end, each BEFORE a barrier (collective
//   guarantee); verified: every half landed before first read. Branchless
//   tail via tile-clamp (rewrites identical bytes — benign); vmcnt(0) once
//   after loop. Raw s_barrier (no drain), setprio around 16-MFMA clusters.
// Used for chunks with rows%256==0 && rows>=8192 (1 blk/CU needs big grids);
// 128x128 2-barrier kernel kept for tails. Ladder {14336,4352} unchanged.
// ---------------------------------------------------------------------------

typedef unsigned short u16;
typedef __attribute__((ext_vector_type(8))) short    bf16x8;
typedef __attribute__((ext_vector_type(4))) float    f32x4;

#define MFMA16(a, b, c) __builtin_amdgcn_mfma_f32_16x16x32_bf16((a), (b), (c), 0, 0, 0)

#define NTRK 192
#define TRI  18528         /* 192*193/2 upper-tri rows incl diagonal */
#define TRIP 18688         /* padded to 146*128 */

__device__ __forceinline__ unsigned int pkbf(float lo, float hi) {
    __hip_bfloat162 h2 = __float22bfloat162_rn(make_float2(lo, hi));
    return *reinterpret_cast<unsigned int*>(&h2);
}
__device__ __forceinline__ void gll16(void* lds_uniform, const void* gsrc) {
    __builtin_amdgcn_global_load_lds(
        (__attribute__((address_space(1))) void*)(gsrc),
        (__attribute__((address_space(3))) void*)(lds_uniform),
        16, 0, 0);
}
// triangle row r -> (i,j), i<=j. T(i) = i*(385-i)/2. Clamped for padding rows.
__device__ __forceinline__ void tri_decode(int r, int& oi, int& oj) {
    double a = 192.5;
    int i = (int)(a - sqrt(a * a - 2.0 * (double)r));
    i = i < 0 ? 0 : (i > 191 ? 191 : i);
    while (i < 191 && (i + 1) * (385 - (i + 1)) / 2 <= r) ++i;
    while (i > 0 && i * (385 - i) / 2 > r) --i;
    int j = i + (r - i * (385 - i) / 2);
    oi = i; oj = j > 191 ? 191 : j;
}

// ---------------------------------------------------------------------------
// All five fp32->bf16 conversions in ONE launch. Segment sizes in f32x4:
// Wc1 4194304 | W1 2097152 | W2 524288 | W3 131072 | f 196608  (sum 7143424)
// ---------------------------------------------------------------------------
#define CVT_N 7143424
__global__ __launch_bounds__(256)
void k_cvt_all(const float* __restrict__ s0, u16* __restrict__ d0,
               const float* __restrict__ s1, u16* __restrict__ d1,
               const float* __restrict__ s2, u16* __restrict__ d2,
               const float* __restrict__ s3, u16* __restrict__ d3,
               const float* __restrict__ s4, u16* __restrict__ d4)
{
    int i = blockIdx.x * 256 + threadIdx.x;
    if (i >= CVT_N) return;
    const float* s; u16* d; int j;
    if      (i < 4194304) { s = s0; d = d0; j = i; }
    else if (i < 6291456) { s = s1; d = d1; j = i - 4194304; }
    else if (i < 6815744) { s = s2; d = d2; j = i - 6291456; }
    else if (i < 6946816) { s = s3; d = d3; j = i - 6815744; }
    else                  { s = s4; d = d4; j = i - 6946816; }
    f32x4 v = ((const f32x4*)s)[j];
    ((uint2*)d)[j] = make_uint2(pkbf(v.x, v.y), pkbf(v.z, v.w));
}

// ---------------------------------------------------------------------------
// cam partials: camp[z][row][col] = (fb @ Wc1b^T) over k in [z*1024,(z+1)*1024)
// M=192,N=4096. BM=64,BN=128,BK=64, split-K=4 via blockIdx.z. grid (3,32,4).
// ---------------------------------------------------------------------------
__global__ __launch_bounds__(256, 2)
void k_cam(const u16* __restrict__ fb, const u16* __restrict__ Wc1b,
           float* __restrict__ camp)
{
    __shared__ __align__(16) u16 As[64 * 64];
    __shared__ __align__(16) u16 Bs[128 * 64];
    const int t = threadIdx.x, l = t & 63, w = t >> 6;
    const int m0 = blockIdx.x * 64, n0 = blockIdx.y * 128;
    const int kbeg = blockIdx.z * 1024, kend = kbeg + 1024;
    const int lr8 = l >> 3;
    const int lc8 = (l & 7) ^ lr8;
    const u16* Ab = fb   + (size_t)(m0 + w * 16 + lr8) * 4096 + lc8 * 8;
    const u16* Bb = Wc1b + (size_t)(n0 + w * 32 + lr8) * 4096 + lc8 * 8;
    f32x4 acc[2][4] = {};
    const int wr = (w >> 1) * 32, wc = (w & 1) * 64;
    const int lrow = l & 15, lq = l >> 4, s = lrow & 7;

    for (int k0 = kbeg; k0 < kend; k0 += 64) {
        __syncthreads();
#pragma unroll
        for (int q = 0; q < 2; ++q)
            gll16(&As[(w * 16 + q * 8) * 64], Ab + (size_t)q * 8 * 4096 + k0);
#pragma unroll
        for (int q = 0; q < 4; ++q)
            gll16(&Bs[(w * 32 + q * 8) * 64], Bb + (size_t)q * 8 * 4096 + k0);
        __syncthreads();
#pragma unroll
        for (int kk8 = 0; kk8 < 8; kk8 += 4) {
            const int co = ((kk8 + lq) ^ s) * 8;
            bf16x8 af[2], bfr[4];
#pragma unroll
            for (int mi = 0; mi < 2; ++mi)
                af[mi] = *(const bf16x8*)&As[(wr + mi * 16 + lrow) * 64 + co];
#pragma unroll
            for (int ni = 0; ni < 4; ++ni)
                bfr[ni] = *(const bf16x8*)&Bs[(wc + ni * 16 + lrow) * 64 + co];
#pragma unroll
            for (int mi = 0; mi < 2; ++mi)
#pragma unroll
                for (int ni = 0; ni < 4; ++ni)
                    acc[mi][ni] = MFMA16(af[mi], bfr[ni], acc[mi][ni]);
        }
    }
    float* cz = camp + (size_t)blockIdx.z * 192 * 4096;
    const int rq = (l >> 4) * 4;
#pragma unroll
    for (int ni = 0; ni < 4; ++ni) {
        const int col = n0 + wc + ni * 16 + lrow;
#pragma unroll
        for (int mi = 0; mi < 2; ++mi) {
            const int rbase = m0 + wr + mi * 16 + rq;
#pragma unroll
            for (int v = 0; v < 4; ++v)
                cz[(size_t)(rbase + v) * 4096 + col] = acc[mi][ni][v];
        }
    }
}

// ---------------------------------------------------------------------------
// g = f - relu(sum_z camp[z] + bc1). 196608 f32x4 groups, grid 768.
// ---------------------------------------------------------------------------
__global__ __launch_bounds__(256)
void k_gfin(const float* __restrict__ camp, const float* __restrict__ bc1,
            const float* __restrict__ f, float* __restrict__ g)
{
    const int i = blockIdx.x * 256 + threadIdx.x;       // < 196608
    const int col4 = (i * 4) & 4095;
    f32x4 p0 = ((const f32x4*)camp)[i];
    f32x4 p1 = ((const f32x4*)(camp + 786432))[i];
    f32x4 p2 = ((const f32x4*)(camp + 1572864))[i];
    f32x4 p3 = ((const f32x4*)(camp + 2359296))[i];
    f32x4 b = *(const f32x4*)(bc1 + col4);
    f32x4 fv = ((const f32x4*)f)[i];
    f32x4 r;
    r.x = fv.x - fmaxf(p0.x + p1.x + p2.x + p3.x + b.x, 0.0f);
    r.y = fv.y - fmaxf(p0.y + p1.y + p2.y + p3.y + b.y, 0.0f);
    r.z = fv.z - fmaxf(p0.z + p1.z + p2.z + p3.z + b.z, 0.0f);
    r.w = fv.w - fmaxf(p0.w + p1.w + p2.w + p3.w + b.w, 0.0f);
    ((f32x4*)g)[i] = r;
}

// ---------------------------------------------------------------------------
// dist[r, :] = bf16(|g_i - g_j|). One 16B chunk per thread. grid (2, rows).
// ---------------------------------------------------------------------------
__global__ __launch_bounds__(256)
void k_distgen(const float* __restrict__ g, u16* __restrict__ dist, int row0)
{
    const int r = blockIdx.y;
    const int c = blockIdx.x * 256 + threadIdx.x;       // chunk 0..511
    int pi, pj; tri_decode(row0 + r, pi, pj);
    const float* gi = g + (size_t)pi * 4096 + c * 8;
    const float* gj = g + (size_t)pj * 4096 + c * 8;
    f32x4 a0 = ((const f32x4*)gi)[0], a1 = ((const f32x4*)gi)[1];
    f32x4 b0 = ((const f32x4*)gj)[0], b1 = ((const f32x4*)gj)[1];
    uint4 o;
    o.x = pkbf(fabsf(b0.x - a0.x), fabsf(b0.y - a0.y));
    o.y = pkbf(fabsf(b0.z - a0.z), fabsf(b0.w - a0.w));
    o.z = pkbf(fabsf(b1.x - a1.x), fabsf(b1.y - a1.y));
    o.w = pkbf(fabsf(b1.z - a1.z), fabsf(b1.w - a1.w));
    *reinterpret_cast<uint4*>(dist + (size_t)r * 4096 + c * 8) = o;
}

// ---------------------------------------------------------------------------
// C = relu(A @ B^T + bias), bf16, 16x16x32 MFMA. BM=BN=128, BK=64, 256 thr,
// wave tile 64x64. grid (N/128, M/128): x = COLUMN tile (fast).
// XOR-swizzled LDS: stage chunk (l&7)^(l>>3), read chunk (ck)^(row&7).
// Used for tail chunks (rows < 8192).
// ---------------------------------------------------------------------------
__global__ __launch_bounds__(256, 2)
void k_gemm_relu(const u16* __restrict__ A, const u16* __restrict__ B,
                 const float* __restrict__ bias, u16* __restrict__ C,
                 int N, int K)
{
    __shared__ __align__(16) u16 As[128 * 64];
    __shared__ __align__(16) u16 Bs[128 * 64];
    const int t = threadIdx.x, l = t & 63, w = t >> 6;
    const int m0 = blockIdx.y * 128, n0 = blockIdx.x * 128;   // x = column!
    const int lr8 = l >> 3;
    const int lc8 = (l & 7) ^ lr8;
    const u16* Ab = A + (size_t)(m0 + w * 32 + lr8) * K + lc8 * 8;
    const u16* Bb = B + (size_t)(n0 + w * 32 + lr8) * K + lc8 * 8;
    f32x4 acc[4][4] = {};
    const int wr = (w >> 1) * 64, wc = (w & 1) * 64;
    const int lrow = l & 15, lq = l >> 4, s = lrow & 7;

    for (int k0 = 0; k0 < K; k0 += 64) {
        __syncthreads();
#pragma unroll
        for (int q = 0; q < 4; ++q) {
            gll16(&As[(w * 32 + q * 8) * 64], Ab + (size_t)q * 8 * K + k0);
            gll16(&Bs[(w * 32 + q * 8) * 64], Bb + (size_t)q * 8 * K + k0);
        }
        __syncthreads();
#pragma unroll
        for (int kk8 = 0; kk8 < 8; kk8 += 4) {
            const int co = ((kk8 + lq) ^ s) * 8;
            bf16x8 af[4], bfr[4];
#pragma unroll
            for (int mi = 0; mi < 4; ++mi)
                af[mi] = *(const bf16x8*)&As[(wr + mi * 16 + lrow) * 64 + co];
#pragma unroll
            for (int ni = 0; ni < 4; ++ni)
                bfr[ni] = *(const bf16x8*)&Bs[(wc + ni * 16 + lrow) * 64 + co];
#pragma unroll
            for (int mi = 0; mi < 4; ++mi)
#pragma unroll
                for (int ni = 0; ni < 4; ++ni)
                    acc[mi][ni] = MFMA16(af[mi], bfr[ni], acc[mi][ni]);
        }
    }
    const int rq = (l >> 4) * 4;
#pragma unroll
    for (int ni = 0; ni < 4; ++ni) {
        const int col = n0 + wc + ni * 16 + lrow;
        const float bv = bias[col];
#pragma unroll
        for (int mi = 0; mi < 4; ++mi) {
            const int rbase = m0 + wr + mi * 16 + rq;
#pragma unroll
            for (int v = 0; v < 4; ++v) {
                float x = fmaxf(acc[mi][ni][v] + bv, 0.0f);
                C[(size_t)(rbase + v) * N + col] = (u16)(pkbf(x, 0.0f) & 0xFFFF);
            }
        }
    }
}

// ---------------------------------------------------------------------------
// 8-phase pipelined 256x256 GEMM: C = relu(A @ B^T + bias). 512 thr, 8 waves
// (wm = w>>2 in {0,1}: rows wm*128..+127; wn = w&3: cols wn*32 & wn*32+128).
// BK=64 per K-tile; 2x double-buffered LDS (128 KiB). See file header for
// the derived schedule + race-freedom proof. M,N % 256 == 0, K % 64 == 0.
// ---------------------------------------------------------------------------
__global__ __launch_bounds__(512, 2)
void k_gemm8(const u16* __restrict__ A, const u16* __restrict__ B,
             const float* __restrict__ bias, u16* __restrict__ C,
             int N, int K)
{
    __shared__ __align__(16) u16 As[2][256 * 64];   // 64 KiB
    __shared__ __align__(16) u16 Bs[2][256 * 64];   // 64 KiB
    const int t = threadIdx.x, l = t & 63, w = t >> 6;
    const int m0 = blockIdx.y * 256, n0 = blockIdx.x * 256;   // x = column
    const int wm = w >> 2, wn = w & 3;
    const int lrow = l & 15, lq = l >> 4, s8 = lrow & 7;
    const int lr8 = l >> 3, lc8 = (l & 7) ^ lr8;
    const int NIT = K >> 6;

    // per-lane staging source bases (row = +w*8+lr8, chunk pre-swizzled)
    const u16* Asrc = A + (size_t)(m0 + w * 8 + lr8) * K + lc8 * 8;
    const u16* Bsrc = B + (size_t)(n0 + w * 8 + lr8) * K + lc8 * 8;

    f32x4 acc[8][4] = {};
    bf16x8 af[4][2], bf[2][2][2];

// stage half-tile half_ of tile_ (clamped) for A (isB_=0) / B (isB_=1):
// 2 x gll16, each covers 64 rows (512 thr x 16B); wave-uniform LDS dst.
#define STG(isB_, tile_, half_) do { \
    const int tt = (tile_) < NIT ? (tile_) : NIT - 1; \
    u16* dst_ = (isB_) ? &Bs[tt & 1][0] : &As[tt & 1][0]; \
    const u16* sb_ = ((isB_) ? Bsrc : Asrc) + (size_t)((half_) * 128) * K + (size_t)tt * 64; \
    gll16(&dst_[((half_) * 128 + w * 8) * 64], sb_); \
    gll16(&dst_[((half_) * 128 + 64 + w * 8) * 64], sb_ + (size_t)64 * K); \
} while (0)

#define RDA(r_) do { \
    _Pragma("unroll") for (int mi = 0; mi < 4; ++mi) { \
        const int row_ = wm * 128 + (r_) * 64 + mi * 16 + lrow; \
        _Pragma("unroll") for (int kk = 0; kk < 2; ++kk) \
            af[mi][kk] = *(const bf16x8*)&Ard[row_ * 64 + ((kk * 4 + lq) ^ s8) * 8]; \
    } \
} while (0)

#define RDB(c_) do { \
    _Pragma("unroll") for (int ni = 0; ni < 2; ++ni) { \
        const int row_ = wn * 32 + (c_) * 128 + ni * 16 + lrow; \
        _Pragma("unroll") for (int kk = 0; kk < 2; ++kk) \
            bf[c_][ni][kk] = *(const bf16x8*)&Brd[row_ * 64 + ((kk * 4 + lq) ^ s8) * 8]; \
    } \
} while (0)

#define MM(r_, c_) do { \
    __builtin_amdgcn_s_setprio(1); \
    _Pragma("unroll") for (int mi = 0; mi < 4; ++mi) \
        _Pragma("unroll") for (int ni = 0; ni < 2; ++ni) \
            _Pragma("unroll") for (int kk = 0; kk < 2; ++kk) \
                acc[(r_) * 4 + mi][(c_) * 2 + ni] = \
                    MFMA16(af[mi][kk], bf[c_][ni][kk], acc[(r_) * 4 + mi][(c_) * 2 + ni]); \
    __builtin_amdgcn_s_setprio(0); \
} while (0)

#define SBAR asm volatile("s_barrier" ::: "memory")

    // prologue: tile0 (4 halves) + A(1,h0); wait tile0 landed (8 oldest).
    STG(0, 0, 0); STG(0, 0, 1); STG(1, 0, 0); STG(1, 0, 1); STG(0, 1, 0);
    asm volatile("s_waitcnt vmcnt(2)" ::: "memory");
    SBAR;

    for (int kt = 0; kt < NIT; ++kt) {
        const u16* Ard = &As[kt & 1][0];
        const u16* Brd = &Bs[kt & 1][0];
        // p1 (r0,c0)
        RDA(0); RDB(0); STG(0, kt + 1, 1);
        SBAR;
        MM(0, 0);
        asm volatile("s_waitcnt vmcnt(4)" ::: "memory");
        SBAR;
        // p2 (r0,c1)
        RDB(1); STG(1, kt + 1, 0);
        SBAR;
        MM(0, 1);
        SBAR;
        // p3 (r1,c0)
        RDA(1); STG(1, kt + 1, 1);
        SBAR;
        MM(1, 0);
        SBAR;
        // p4 (r1,c1)
        STG(0, kt + 2, 0);
        SBAR;
        MM(1, 1);
        asm volatile("s_waitcnt vmcnt(4)" ::: "memory");
        SBAR;
    }
    asm volatile("s_waitcnt vmcnt(0)" ::: "memory");
#undef STG
#undef RDA
#undef RDB
#undef MM
#undef SBAR

    // epilogue: row = m0+wm*128+r*64+mi*16+lq*4+v ; col = n0+wn*32+c*128+ni*16+lrow
#pragma unroll
    for (int c = 0; c < 2; ++c)
#pragma unroll
        for (int ni = 0; ni < 2; ++ni) {
            const int col = n0 + wn * 32 + c * 128 + ni * 16 + lrow;
            const float bv = bias[col];
#pragma unroll
            for (int r = 0; r < 2; ++r)
#pragma unroll
                for (int mi = 0; mi < 4; ++mi) {
                    const int rbase = m0 + wm * 128 + r * 64 + mi * 16 + lq * 4;
#pragma unroll
                    for (int v = 0; v < 4; ++v) {
                        float x = fmaxf(acc[r * 4 + mi][c * 2 + ni][v] + bv, 0.0f);
                        C[(size_t)(rbase + v) * N + col] = (u16)(pkbf(x, 0.0f) & 0xFFFF);
                    }
                }
        }
}

// ---------------------------------------------------------------------------
// Fused L3+head: logit[r0+row] += sum_col relu(h2@W3^T + b3)[row,col]*Ws[col].
// 16x16 GEMM core (N=512, K=1024, grid (4, rows/128)). Epilogue: per (mi,v)
// row-slot, dot partial over this lane's 4 cols, butterfly-reduce across the
// 16 lrow lanes, one fp32 atomicAdd per row-slot from lane lrow==0.
// ---------------------------------------------------------------------------
__global__ __launch_bounds__(256, 2)
void k_gemm3(const u16* __restrict__ A, const u16* __restrict__ B,
             const float* __restrict__ bias, const float* __restrict__ Wsv,
             float* __restrict__ logit, int r0)
{
    const int N = 512, K = 1024;
    __shared__ __align__(16) u16 As[128 * 64];
    __shared__ __align__(16) u16 Bs[128 * 64];
    const int t = threadIdx.x, l = t & 63, w = t >> 6;
    const int m0 = blockIdx.y * 128, n0 = blockIdx.x * 128;
    const int lr8 = l >> 3;
    const int lc8 = (l & 7) ^ lr8;
    const u16* Ab = A + (size_t)(m0 + w * 32 + lr8) * K + lc8 * 8;
    const u16* Bb = B + (size_t)(n0 + w * 32 + lr8) * K + lc8 * 8;
    f32x4 acc[4][4] = {};
    const int wr = (w >> 1) * 64, wc = (w & 1) * 64;
    const int lrow = l & 15, lq = l >> 4, s = lrow & 7;

    for (int k0 = 0; k0 < K; k0 += 64) {
        __syncthreads();
#pragma unroll
        for (int q = 0; q < 4; ++q) {
            gll16(&As[(w * 32 + q * 8) * 64], Ab + (size_t)q * 8 * K + k0);
            gll16(&Bs[(w * 32 + q * 8) * 64], Bb + (size_t)q * 8 * K + k0);
        }
        __syncthreads();
#pragma unroll
        for (int kk8 = 0; kk8 < 8; kk8 += 4) {
            const int co = ((kk8 + lq) ^ s) * 8;
            bf16x8 af[4], bfr[4];
#pragma unroll
            for (int mi = 0; mi < 4; ++mi)
                af[mi] = *(const bf16x8*)&As[(wr + mi * 16 + lrow) * 64 + co];
#pragma unroll
            for (int ni = 0; ni < 4; ++ni)
                bfr[ni] = *(const bf16x8*)&Bs[(wc + ni * 16 + lrow) * 64 + co];
#pragma unroll
            for (int mi = 0; mi < 4; ++mi)
#pragma unroll
                for (int ni = 0; ni < 4; ++ni)
                    acc[mi][ni] = MFMA16(af[mi], bfr[ni], acc[mi][ni]);
        }
    }
    const int rq = (l >> 4) * 4;
    float wv[4], bv[4];
#pragma unroll
    for (int ni = 0; ni < 4; ++ni) {
        const int col = n0 + wc + ni * 16 + lrow;
        wv[ni] = Wsv[col];
        bv[ni] = bias[col];
    }
#pragma unroll
    for (int mi = 0; mi < 4; ++mi) {
#pragma unroll
        for (int v = 0; v < 4; ++v) {
            float p = 0.0f;
#pragma unroll
            for (int ni = 0; ni < 4; ++ni)
                p += fmaxf(acc[mi][ni][v] + bv[ni], 0.0f) * wv[ni];
            p += __shfl_xor(p, 1, 64);
            p += __shfl_xor(p, 2, 64);
            p += __shfl_xor(p, 4, 64);
            p += __shfl_xor(p, 8, 64);
            if (lrow == 0)
                atomicAdd(&logit[r0 + m0 + wr + mi * 16 + rq + v], p);
        }
    }
}

// ---------------------------------------------------------------------------
// out[i,j] = out[j,i] = sigmoid(logit[r] + bs). One thread per tri-row.
// ---------------------------------------------------------------------------
__global__ __launch_bounds__(256)
void k_sig(const float* __restrict__ logit, const float* __restrict__ bsv,
           float* __restrict__ out)
{
    const int r = blockIdx.x * 256 + threadIdx.x;
    if (r >= TRI) return;
    int pi, pj; tri_decode(r, pi, pj);
    float v = 1.0f / (1.0f + __expf(-(logit[r] + bsv[0])));
    out[pi * NTRK + pj] = v;
    out[pj * NTRK + pi] = v;
}

// ---------------------------------------------------------------------------
extern "C" void kernel_launch(void* const* d_in, const int* in_sizes, int n_in,
                              void* d_out, int out_size, void* d_ws, size_t ws_size,
                              hipStream_t stream)
{
    const float* f   = (const float*)d_in[0];
    const float* Wc1 = (const float*)d_in[1];
    const float* bc1 = (const float*)d_in[2];
    const float* W1  = (const float*)d_in[3];
    const float* b1  = (const float*)d_in[4];
    const float* W2  = (const float*)d_in[5];
    const float* b2  = (const float*)d_in[6];
    const float* W3  = (const float*)d_in[7];
    const float* b3  = (const float*)d_in[8];
    const float* Wsv = (const float*)d_in[9];
    const float* bsv = (const float*)d_in[10];
    float* out = (float*)d_out;

    // ---- workspace layout ----
    // persistent: W1b 16M | W2b 4M | W3b 1M | fb 1.5M | g 3M | logit 75K
    // overlay region at chunkbase:
    //   phase A: Wc1b (32M) + camp (12M)   [dead before chunk loop]
    //   phase B: dist (8192R) + h1 (4096R); h2 (2048R) overlays dist.
    char* wsb = (char*)d_ws;
    size_t off = 0;
    u16*   W1b   = (u16*)(wsb + off);  off += (size_t)2048 * 4096 * 2;
    u16*   W2b   = (u16*)(wsb + off);  off += (size_t)1024 * 2048 * 2;
    u16*   W3b   = (u16*)(wsb + off);  off += (size_t)512  * 1024 * 2;
    u16*   fb    = (u16*)(wsb + off);  off += (size_t)192  * 4096 * 2;
    float* g     = (float*)(wsb + off); off += (size_t)192 * 4096 * 4;
    float* logit = (float*)(wsb + off); off += (size_t)TRIP * 4;
    const size_t chunkbase = off;
    u16*   Wc1b = (u16*)(wsb + chunkbase);
    float* camp = (float*)(wsb + chunkbase + (size_t)4096 * 4096 * 2);
    const size_t phaseA = (size_t)4096 * 4096 * 2 + (size_t)4 * 192 * 4096 * 4;

    // measured-best asymmetric ladder (round-9).
    const int Rcand[6] = {18688, 14336, 9344, 4736, 2432, 1280};
    int R = 128;
    for (int c = 0; c < 6; ++c) {
        size_t chunk = (size_t)Rcand[c] * 12288;
        if (chunk < phaseA) chunk = phaseA;
        if (chunkbase + chunk <= ws_size) { R = Rcand[c]; break; }
    }
    u16* dist = (u16*)(wsb + chunkbase);
    u16* h1 = dist + (size_t)R * 4096;
    u16* h2 = dist;                       // overlays dist (dead after L1)

    hipMemsetAsync(logit, 0, (size_t)TRIP * 4, stream);
    k_cvt_all<<<(CVT_N + 255) / 256, 256, 0, stream>>>(
        Wc1, Wc1b, W1, W1b, W2, W2b, W3, W3b, f, fb);
    k_cam<<<dim3(3, 32, 4), 256, 0, stream>>>(fb, Wc1b, camp);
    k_gfin<<<768, 256, 0, stream>>>(camp, bc1, f, g);

    for (int r0 = 0; r0 < TRI; r0 += R) {
        int rows = TRIP - r0; if (rows > R) rows = R;   // mult of 128
        k_distgen<<<dim3(2, rows), 256, 0, stream>>>(g, dist, r0);
        if ((rows & 255) == 0 && rows >= 8192) {
            k_gemm8<<<dim3(8, rows / 256), 512, 0, stream>>>(dist, W1b, b1, h1, 2048, 4096);
            k_gemm8<<<dim3(4, rows / 256), 512, 0, stream>>>(h1, W2b, b2, h2, 1024, 2048);
        } else {
            k_gemm_relu<<<dim3(16, rows / 128), 256, 0, stream>>>(dist, W1b, b1, h1, 2048, 4096);
            k_gemm_relu<<<dim3(8,  rows / 128), 256, 0, stream>>>(h1, W2b, b2, h2, 1024, 2048);
        }
        k_gemm3<<<dim3(4, rows / 128), 256, 0, stream>>>(h2, W3b, b3, Wsv, logit, r0);
    }
    k_sig<<<(TRI + 255) / 256, 256, 0, stream>>>(logit, bsv, out);
}

// Round 8
// 658.228 us; speedup vs baseline: 1.1229x; 1.0607x over previous
//
#include <hip/hip_runtime.h>
#include <hip/hip_bf16.h>

// ---------------------------------------------------------------------------
// MCT tracklet-affinity pipeline. fp32 in/out, bf16 MFMA internally.
//   g    = f - relu(f @ Wc1^T + bc1)             [192,4096] fp32 in ws
//   dist = |g_i - g_j| for upper-tri rows        [R,4096] bf16, materialized
//   h1   = relu(dist @ W1^T + b1)                [R,2048] bf16
//   h2   = relu(h1 @ W2^T + b2)                  [R,1024]  (overlays dist)
//   logit[r] += relu(h2 @ W3^T + b3) . Ws        (k_gemm3: fused L3+head dot)
//   A[i,j]=A[j,i]=sigmoid(logit + bs)            (k_sig, once at end)
// Round-17 == round-16 resubmit (container failed twice; audit found no
// device hazard: staging layout equivalence verified, bounds in range,
// sync structure unchanged).
// Round-16: revert to proven round-9 config + ONE change: k_cam stages its
// B operand directly from fp32 Wc1 (reg-staging: 2xf32x4 -> cvt_pk ->
// ds_write_b128), so Wc1 is dropped from k_cvt_all (-96 MB HBM traffic).
// Write swizzle preserves the proven read layout LDS[r][c]=G[r][c^(r&7)]:
// load global chunk l&7, write LDS chunk (l&7)^(l>>3); each 8-lane write
// phase covers 8 distinct chunks -> conflict-free.
// GEMM core (unchanged, at structural ceiling): 16x16x32 MFMA, XOR-swizzled
// LDS (0 conflicts), global_load_lds width-16, 2-barrier K-loop, x=col tile.
// ---------------------------------------------------------------------------

typedef unsigned short u16;
typedef __attribute__((ext_vector_type(8))) short    bf16x8;
typedef __attribute__((ext_vector_type(4))) float    f32x4;

#define MFMA16(a, b, c) __builtin_amdgcn_mfma_f32_16x16x32_bf16((a), (b), (c), 0, 0, 0)

#define NTRK 192
#define TRI  18528         /* 192*193/2 upper-tri rows incl diagonal */
#define TRIP 18688         /* padded to 146*128 */

__device__ __forceinline__ unsigned int pkbf(float lo, float hi) {
    __hip_bfloat162 h2 = __float22bfloat162_rn(make_float2(lo, hi));
    return *reinterpret_cast<unsigned int*>(&h2);
}
__device__ __forceinline__ void gll16(void* lds_uniform, const void* gsrc) {
    __builtin_amdgcn_global_load_lds(
        (__attribute__((address_space(1))) void*)(gsrc),
        (__attribute__((address_space(3))) void*)(lds_uniform),
        16, 0, 0);
}
// triangle row r -> (i,j), i<=j. T(i) = i*(385-i)/2. Clamped for padding rows.
__device__ __forceinline__ void tri_decode(int r, int& oi, int& oj) {
    double a = 192.5;
    int i = (int)(a - sqrt(a * a - 2.0 * (double)r));
    i = i < 0 ? 0 : (i > 191 ? 191 : i);
    while (i < 191 && (i + 1) * (385 - (i + 1)) / 2 <= r) ++i;
    while (i > 0 && i * (385 - i) / 2 > r) --i;
    int j = i + (r - i * (385 - i) / 2);
    oi = i; oj = j > 191 ? 191 : j;
}

// ---------------------------------------------------------------------------
// Four fp32->bf16 conversions in ONE launch (Wc1 no longer converted — k_cam
// reads it fp32 directly). Segment sizes in f32x4:
// W1 2097152 | W2 524288 | W3 131072 | f 196608  (sum 2949120)
// ---------------------------------------------------------------------------
#define CVT_N 2949120
__global__ __launch_bounds__(256)
void k_cvt_all(const float* __restrict__ s1, u16* __restrict__ d1,
               const float* __restrict__ s2, u16* __restrict__ d2,
               const float* __restrict__ s3, u16* __restrict__ d3,
               const float* __restrict__ s4, u16* __restrict__ d4)
{
    int i = blockIdx.x * 256 + threadIdx.x;
    if (i >= CVT_N) return;
    const float* s; u16* d; int j;
    if      (i < 2097152) { s = s1; d = d1; j = i; }
    else if (i < 2621440) { s = s2; d = d2; j = i - 2097152; }
    else if (i < 2752512) { s = s3; d = d3; j = i - 2621440; }
    else                  { s = s4; d = d4; j = i - 2752512; }
    f32x4 v = ((const f32x4*)s)[j];
    ((uint2*)d)[j] = make_uint2(pkbf(v.x, v.y), pkbf(v.z, v.w));
}

// ---------------------------------------------------------------------------
// cam partials: camp[z][row][col] = (fb @ Wc1^T) over k in [z*1024,(z+1)*1024)
// M=192,N=4096. BM=64,BN=128,BK=64, split-K=4 via blockIdx.z. grid (3,32,4).
// B staged from fp32 Wc1 via registers (load 2xf32x4, cvt_pk, ds_write_b128);
// write chunk (l&7)^lr8 reproduces LDS[r][c]=G[r][c^(r&7)], so the read side
// (co = k ^ (row&7)) is unchanged. A (fb bf16) stays on global_load_lds.
// ---------------------------------------------------------------------------
__global__ __launch_bounds__(256, 2)
void k_cam(const u16* __restrict__ fb, const float* __restrict__ Wc1,
           float* __restrict__ camp)
{
    __shared__ __align__(16) u16 As[64 * 64];
    __shared__ __align__(16) u16 Bs[128 * 64];
    const int t = threadIdx.x, l = t & 63, w = t >> 6;
    const int m0 = blockIdx.x * 64, n0 = blockIdx.y * 128;
    const int kbeg = blockIdx.z * 1024, kend = kbeg + 1024;
    const int lr8 = l >> 3;
    const int lc8 = (l & 7) ^ lr8;
    const u16*  Ab = fb  + (size_t)(m0 + w * 16 + lr8) * 4096 + lc8 * 8;
    const float* Bb = Wc1 + (size_t)(n0 + w * 32 + lr8) * 4096 + (l & 7) * 8;
    u16* Bw = &Bs[(w * 32 + lr8) * 64 + ((l & 7) ^ lr8) * 8];
    f32x4 acc[2][4] = {};
    const int wr = (w >> 1) * 32, wc = (w & 1) * 64;
    const int lrow = l & 15, lq = l >> 4, s = lrow & 7;

    for (int k0 = kbeg; k0 < kend; k0 += 64) {
        __syncthreads();
#pragma unroll
        for (int q = 0; q < 2; ++q)
            gll16(&As[(w * 16 + q * 8) * 64], Ab + (size_t)q * 8 * 4096 + k0);
#pragma unroll
        for (int q = 0; q < 4; ++q) {
            const float* src = Bb + (size_t)q * 8 * 4096 + k0;
            f32x4 v0 = ((const f32x4*)src)[0];
            f32x4 v1 = ((const f32x4*)src)[1];
            uint4 o;
            o.x = pkbf(v0.x, v0.y); o.y = pkbf(v0.z, v0.w);
            o.z = pkbf(v1.x, v1.y); o.w = pkbf(v1.z, v1.w);
            *reinterpret_cast<uint4*>(Bw + q * 8 * 64) = o;
        }
        __syncthreads();
#pragma unroll
        for (int kk8 = 0; kk8 < 8; kk8 += 4) {
            const int co = ((kk8 + lq) ^ s) * 8;
            bf16x8 af[2], bfr[4];
#pragma unroll
            for (int mi = 0; mi < 2; ++mi)
                af[mi] = *(const bf16x8*)&As[(wr + mi * 16 + lrow) * 64 + co];
#pragma unroll
            for (int ni = 0; ni < 4; ++ni)
                bfr[ni] = *(const bf16x8*)&Bs[(wc + ni * 16 + lrow) * 64 + co];
#pragma unroll
            for (int mi = 0; mi < 2; ++mi)
#pragma unroll
                for (int ni = 0; ni < 4; ++ni)
                    acc[mi][ni] = MFMA16(af[mi], bfr[ni], acc[mi][ni]);
        }
    }
    float* cz = camp + (size_t)blockIdx.z * 192 * 4096;
    const int rq = (l >> 4) * 4;
#pragma unroll
    for (int ni = 0; ni < 4; ++ni) {
        const int col = n0 + wc + ni * 16 + lrow;
#pragma unroll
        for (int mi = 0; mi < 2; ++mi) {
            const int rbase = m0 + wr + mi * 16 + rq;
#pragma unroll
            for (int v = 0; v < 4; ++v)
                cz[(size_t)(rbase + v) * 4096 + col] = acc[mi][ni][v];
        }
    }
}

// ---------------------------------------------------------------------------
// g = f - relu(sum_z camp[z] + bc1). 196608 f32x4 groups, grid 768.
// ---------------------------------------------------------------------------
__global__ __launch_bounds__(256)
void k_gfin(const float* __restrict__ camp, const float* __restrict__ bc1,
            const float* __restrict__ f, float* __restrict__ g)
{
    const int i = blockIdx.x * 256 + threadIdx.x;       // < 196608
    const int col4 = (i * 4) & 4095;
    f32x4 p0 = ((const f32x4*)camp)[i];
    f32x4 p1 = ((const f32x4*)(camp + 786432))[i];
    f32x4 p2 = ((const f32x4*)(camp + 1572864))[i];
    f32x4 p3 = ((const f32x4*)(camp + 2359296))[i];
    f32x4 b = *(const f32x4*)(bc1 + col4);
    f32x4 fv = ((const f32x4*)f)[i];
    f32x4 r;
    r.x = fv.x - fmaxf(p0.x + p1.x + p2.x + p3.x + b.x, 0.0f);
    r.y = fv.y - fmaxf(p0.y + p1.y + p2.y + p3.y + b.y, 0.0f);
    r.z = fv.z - fmaxf(p0.z + p1.z + p2.z + p3.z + b.z, 0.0f);
    r.w = fv.w - fmaxf(p0.w + p1.w + p2.w + p3.w + b.w, 0.0f);
    ((f32x4*)g)[i] = r;
}

// ---------------------------------------------------------------------------
// dist[r, :] = bf16(|g_i - g_j|). One 16B chunk per thread. grid (2, rows).
// ---------------------------------------------------------------------------
__global__ __launch_bounds__(256)
void k_distgen(const float* __restrict__ g, u16* __restrict__ dist, int row0)
{
    const int r = blockIdx.y;
    const int c = blockIdx.x * 256 + threadIdx.x;       // chunk 0..511
    int pi, pj; tri_decode(row0 + r, pi, pj);
    const float* gi = g + (size_t)pi * 4096 + c * 8;
    const float* gj = g + (size_t)pj * 4096 + c * 8;
    f32x4 a0 = ((const f32x4*)gi)[0], a1 = ((const f32x4*)gi)[1];
    f32x4 b0 = ((const f32x4*)gj)[0], b1 = ((const f32x4*)gj)[1];
    uint4 o;
    o.x = pkbf(fabsf(b0.x - a0.x), fabsf(b0.y - a0.y));
    o.y = pkbf(fabsf(b0.z - a0.z), fabsf(b0.w - a0.w));
    o.z = pkbf(fabsf(b1.x - a1.x), fabsf(b1.y - a1.y));
    o.w = pkbf(fabsf(b1.z - a1.z), fabsf(b1.w - a1.w));
    *reinterpret_cast<uint4*>(dist + (size_t)r * 4096 + c * 8) = o;
}

// ---------------------------------------------------------------------------
// C = relu(A @ B^T + bias), bf16, 16x16x32 MFMA. BM=BN=128, BK=64, 256 thr,
// wave tile 64x64. grid (N/128, M/128): x = COLUMN tile (fast).
// XOR-swizzled LDS: stage chunk (l&7)^(l>>3), read chunk (ck)^(row&7).
// ---------------------------------------------------------------------------
__global__ __launch_bounds__(256, 2)
void k_gemm_relu(const u16* __restrict__ A, const u16* __restrict__ B,
                 const float* __restrict__ bias, u16* __restrict__ C,
                 int N, int K)
{
    __shared__ __align__(16) u16 As[128 * 64];
    __shared__ __align__(16) u16 Bs[128 * 64];
    const int t = threadIdx.x, l = t & 63, w = t >> 6;
    const int m0 = blockIdx.y * 128, n0 = blockIdx.x * 128;   // x = column!
    const int lr8 = l >> 3;
    const int lc8 = (l & 7) ^ lr8;
    const u16* Ab = A + (size_t)(m0 + w * 32 + lr8) * K + lc8 * 8;
    const u16* Bb = B + (size_t)(n0 + w * 32 + lr8) * K + lc8 * 8;
    f32x4 acc[4][4] = {};
    const int wr = (w >> 1) * 64, wc = (w & 1) * 64;
    const int lrow = l & 15, lq = l >> 4, s = lrow & 7;

    for (int k0 = 0; k0 < K; k0 += 64) {
        __syncthreads();
#pragma unroll
        for (int q = 0; q < 4; ++q) {
            gll16(&As[(w * 32 + q * 8) * 64], Ab + (size_t)q * 8 * K + k0);
            gll16(&Bs[(w * 32 + q * 8) * 64], Bb + (size_t)q * 8 * K + k0);
        }
        __syncthreads();
#pragma unroll
        for (int kk8 = 0; kk8 < 8; kk8 += 4) {
            const int co = ((kk8 + lq) ^ s) * 8;
            bf16x8 af[4], bfr[4];
#pragma unroll
            for (int mi = 0; mi < 4; ++mi)
                af[mi] = *(const bf16x8*)&As[(wr + mi * 16 + lrow) * 64 + co];
#pragma unroll
            for (int ni = 0; ni < 4; ++ni)
                bfr[ni] = *(const bf16x8*)&Bs[(wc + ni * 16 + lrow) * 64 + co];
#pragma unroll
            for (int mi = 0; mi < 4; ++mi)
#pragma unroll
                for (int ni = 0; ni < 4; ++ni)
                    acc[mi][ni] = MFMA16(af[mi], bfr[ni], acc[mi][ni]);
        }
    }
    const int rq = (l >> 4) * 4;
#pragma unroll
    for (int ni = 0; ni < 4; ++ni) {
        const int col = n0 + wc + ni * 16 + lrow;
        const float bv = bias[col];
#pragma unroll
        for (int mi = 0; mi < 4; ++mi) {
            const int rbase = m0 + wr + mi * 16 + rq;
#pragma unroll
            for (int v = 0; v < 4; ++v) {
                float x = fmaxf(acc[mi][ni][v] + bv, 0.0f);
                C[(size_t)(rbase + v) * N + col] = (u16)(pkbf(x, 0.0f) & 0xFFFF);
            }
        }
    }
}

// ---------------------------------------------------------------------------
// Fused L3+head: logit[r0+row] += sum_col relu(h2@W3^T + b3)[row,col]*Ws[col].
// Same GEMM core (N=512, K=1024, grid (4, rows/128)). Epilogue: per (mi,v)
// row-slot, dot partial over this lane's 4 cols, butterfly-reduce across the
// 16 lrow lanes (xor masks 1,2,4,8 stay within the l>>4 quad since row is
// determined by l>>4), one fp32 atomicAdd per row-slot from lane lrow==0.
// ---------------------------------------------------------------------------
__global__ __launch_bounds__(256, 2)
void k_gemm3(const u16* __restrict__ A, const u16* __restrict__ B,
             const float* __restrict__ bias, const float* __restrict__ Wsv,
             float* __restrict__ logit, int r0)
{
    const int N = 512, K = 1024;
    __shared__ __align__(16) u16 As[128 * 64];
    __shared__ __align__(16) u16 Bs[128 * 64];
    const int t = threadIdx.x, l = t & 63, w = t >> 6;
    const int m0 = blockIdx.y * 128, n0 = blockIdx.x * 128;
    const int lr8 = l >> 3;
    const int lc8 = (l & 7) ^ lr8;
    const u16* Ab = A + (size_t)(m0 + w * 32 + lr8) * K + lc8 * 8;
    const u16* Bb = B + (size_t)(n0 + w * 32 + lr8) * K + lc8 * 8;
    f32x4 acc[4][4] = {};
    const int wr = (w >> 1) * 64, wc = (w & 1) * 64;
    const int lrow = l & 15, lq = l >> 4, s = lrow & 7;

    for (int k0 = 0; k0 < K; k0 += 64) {
        __syncthreads();
#pragma unroll
        for (int q = 0; q < 4; ++q) {
            gll16(&As[(w * 32 + q * 8) * 64], Ab + (size_t)q * 8 * K + k0);
            gll16(&Bs[(w * 32 + q * 8) * 64], Bb + (size_t)q * 8 * K + k0);
        }
        __syncthreads();
#pragma unroll
        for (int kk8 = 0; kk8 < 8; kk8 += 4) {
            const int co = ((kk8 + lq) ^ s) * 8;
            bf16x8 af[4], bfr[4];
#pragma unroll
            for (int mi = 0; mi < 4; ++mi)
                af[mi] = *(const bf16x8*)&As[(wr + mi * 16 + lrow) * 64 + co];
#pragma unroll
            for (int ni = 0; ni < 4; ++ni)
                bfr[ni] = *(const bf16x8*)&Bs[(wc + ni * 16 + lrow) * 64 + co];
#pragma unroll
            for (int mi = 0; mi < 4; ++mi)
#pragma unroll
                for (int ni = 0; ni < 4; ++ni)
                    acc[mi][ni] = MFMA16(af[mi], bfr[ni], acc[mi][ni]);
        }
    }
    const int rq = (l >> 4) * 4;
    float wv[4], bv[4];
#pragma unroll
    for (int ni = 0; ni < 4; ++ni) {
        const int col = n0 + wc + ni * 16 + lrow;
        wv[ni] = Wsv[col];
        bv[ni] = bias[col];
    }
#pragma unroll
    for (int mi = 0; mi < 4; ++mi) {
#pragma unroll
        for (int v = 0; v < 4; ++v) {
            float p = 0.0f;
#pragma unroll
            for (int ni = 0; ni < 4; ++ni)
                p += fmaxf(acc[mi][ni][v] + bv[ni], 0.0f) * wv[ni];
            p += __shfl_xor(p, 1, 64);
            p += __shfl_xor(p, 2, 64);
            p += __shfl_xor(p, 4, 64);
            p += __shfl_xor(p, 8, 64);
            if (lrow == 0)
                atomicAdd(&logit[r0 + m0 + wr + mi * 16 + rq + v], p);
        }
    }
}

// ---------------------------------------------------------------------------
// out[i,j] = out[j,i] = sigmoid(logit[r] + bs). One thread per tri-row.
// ---------------------------------------------------------------------------
__global__ __launch_bounds__(256)
void k_sig(const float* __restrict__ logit, const float* __restrict__ bsv,
           float* __restrict__ out)
{
    const int r = blockIdx.x * 256 + threadIdx.x;
    if (r >= TRI) return;
    int pi, pj; tri_decode(r, pi, pj);
    float v = 1.0f / (1.0f + __expf(-(logit[r] + bsv[0])));
    out[pi * NTRK + pj] = v;
    out[pj * NTRK + pi] = v;
}

// ---------------------------------------------------------------------------
extern "C" void kernel_launch(void* const* d_in, const int* in_sizes, int n_in,
                              void* d_out, int out_size, void* d_ws, size_t ws_size,
                              hipStream_t stream)
{
    const float* f   = (const float*)d_in[0];
    const float* Wc1 = (const float*)d_in[1];
    const float* bc1 = (const float*)d_in[2];
    const float* W1  = (const float*)d_in[3];
    const float* b1  = (const float*)d_in[4];
    const float* W2  = (const float*)d_in[5];
    const float* b2  = (const float*)d_in[6];
    const float* W3  = (const float*)d_in[7];
    const float* b3  = (const float*)d_in[8];
    const float* Wsv = (const float*)d_in[9];
    const float* bsv = (const float*)d_in[10];
    float* out = (float*)d_out;

    // ---- workspace layout ----
    // persistent: W1b 16M | W2b 4M | W3b 1M | fb 1.5M | g 3M | logit 75K
    // overlay region at chunkbase:
    //   phase A: camp (12M)   [dead before chunk loop; Wc1b eliminated]
    //   phase B: dist (8192R) + h1 (4096R); h2 (2048R) overlays dist.
    char* wsb = (char*)d_ws;
    size_t off = 0;
    u16*   W1b   = (u16*)(wsb + off);  off += (size_t)2048 * 4096 * 2;
    u16*   W2b   = (u16*)(wsb + off);  off += (size_t)1024 * 2048 * 2;
    u16*   W3b   = (u16*)(wsb + off);  off += (size_t)512  * 1024 * 2;
    u16*   fb    = (u16*)(wsb + off);  off += (size_t)192  * 4096 * 2;
    float* g     = (float*)(wsb + off); off += (size_t)192 * 4096 * 4;
    float* logit = (float*)(wsb + off); off += (size_t)TRIP * 4;
    const size_t chunkbase = off;
    float* camp = (float*)(wsb + chunkbase);
    const size_t phaseA = (size_t)4 * 192 * 4096 * 4;

    // measured-best asymmetric ladder (round-9).
    const int Rcand[6] = {18688, 14336, 9344, 4736, 2432, 1280};
    int R = 128;
    for (int c = 0; c < 6; ++c) {
        size_t chunk = (size_t)Rcand[c] * 12288;
        if (chunk < phaseA) chunk = phaseA;
        if (chunkbase + chunk <= ws_size) { R = Rcand[c]; break; }
    }
    u16* dist = (u16*)(wsb + chunkbase);
    u16* h1 = dist + (size_t)R * 4096;
    u16* h2 = dist;                       // overlays dist (dead after L1)

    hipMemsetAsync(logit, 0, (size_t)TRIP * 4, stream);
    k_cvt_all<<<(CVT_N + 255) / 256, 256, 0, stream>>>(
        W1, W1b, W2, W2b, W3, W3b, f, fb);
    k_cam<<<dim3(3, 32, 4), 256, 0, stream>>>(fb, Wc1, camp);
    k_gfin<<<768, 256, 0, stream>>>(camp, bc1, f, g);

    for (int r0 = 0; r0 < TRI; r0 += R) {
        int rows = TRIP - r0; if (rows > R) rows = R;   // mult of 128
        k_distgen<<<dim3(2, rows), 256, 0, stream>>>(g, dist, r0);
        k_gemm_relu<<<dim3(16, rows / 128), 256, 0, stream>>>(dist, W1b, b1, h1, 2048, 4096);
        k_gemm_relu<<<dim3(8,  rows / 128), 256, 0, stream>>>(h1, W2b, b2, h2, 1024, 2048);
        k_gemm3<<<dim3(4, rows / 128), 256, 0, stream>>>(h2, W3b, b3, Wsv, logit, r0);
    }
    k_sig<<<(TRI + 255) / 256, 256, 0, stream>>>(logit, bsv, out);
}

// Round 9
// 644.000 us; speedup vs baseline: 1.1477x; 1.0221x over previous
//
#include <hip/hip_runtime.h>
#include <hip/hip_bf16.h>

// ---------------------------------------------------------------------------
// MCT tracklet-affinity pipeline. fp32 in/out, bf16 MFMA internally.
//   g    = f - relu(f @ Wc1^T + bc1)             [192,4096] fp32 in ws
//   dist = |g_i - g_j| for upper-tri rows        [R,4096] bf16, materialized
//   h1   = relu(dist @ W1^T + b1)                [R,2048] bf16
//   h2   = relu(h1 @ W2^T + b2)                  [R,1024]  (overlays dist)
//   logit[r] += relu(h2 @ W3^T + b3) . Ws        (k_gemm3: fused L3+head dot,
//                                                 fp32 atomicAdd per row)
//   A[i,j]=A[j,i]=sigmoid(logit + bs)            (k_sig, once at end)
// Round-18: FINAL restore of the empirically-best round-9 configuration
// (642.6 us; independently reproduced at 644.7). Nine falsifiable
// experiments all measured negative or neutral:
//   8-phase 256^2 x2 (-129/-56us: m232 derived-waits failure, 589/689 TF vs
//   802 TF for this 2-barrier core), 32x32x16 core (-70us: 3.8e7 LDS
//   conflicts), XCD column-band swizzle (-96us: FETCH x1.8 — default %8
//   round-robin already at per-XCD-L2 optimum), chunk repack (neutral:
//   dispatch time not block-count-proportional), cvt-Wc1->cam fusion
//   (-16us: L1 FETCH regression swamped cvt savings).
// Structural position: L1 GEMM at 802 TF = 89% of the measured ~900 TF
// 2-barrier-structure ceiling; FETCH at per-XCD-L2 analytical optimum;
// 0 bank conflicts; non-GEMM kernels < 25% of total with no single >10us
// opportunity. Remaining headroom requires the exact m201 pipeline
// schedule, which two independent derivations failed to reproduce here.
// GEMM core: 16x16x32 MFMA, XOR-swizzled LDS (stage chunk (l&7)^(l>>3),
// read chunk k^(row&7)), global_load_lds width-16, 2-barrier K-loop,
// x = column tile for L2 locality. Chunk ladder {14336, 4352}.
// ---------------------------------------------------------------------------

typedef unsigned short u16;
typedef __attribute__((ext_vector_type(8))) short    bf16x8;
typedef __attribute__((ext_vector_type(4))) float    f32x4;

#define MFMA16(a, b, c) __builtin_amdgcn_mfma_f32_16x16x32_bf16((a), (b), (c), 0, 0, 0)

#define NTRK 192
#define TRI  18528         /* 192*193/2 upper-tri rows incl diagonal */
#define TRIP 18688         /* padded to 146*128 */

__device__ __forceinline__ unsigned int pkbf(float lo, float hi) {
    __hip_bfloat162 h2 = __float22bfloat162_rn(make_float2(lo, hi));
    return *reinterpret_cast<unsigned int*>(&h2);
}
__device__ __forceinline__ void gll16(void* lds_uniform, const void* gsrc) {
    __builtin_amdgcn_global_load_lds(
        (__attribute__((address_space(1))) void*)(gsrc),
        (__attribute__((address_space(3))) void*)(lds_uniform),
        16, 0, 0);
}
// triangle row r -> (i,j), i<=j. T(i) = i*(385-i)/2. Clamped for padding rows.
__device__ __forceinline__ void tri_decode(int r, int& oi, int& oj) {
    double a = 192.5;
    int i = (int)(a - sqrt(a * a - 2.0 * (double)r));
    i = i < 0 ? 0 : (i > 191 ? 191 : i);
    while (i < 191 && (i + 1) * (385 - (i + 1)) / 2 <= r) ++i;
    while (i > 0 && i * (385 - i) / 2 > r) --i;
    int j = i + (r - i * (385 - i) / 2);
    oi = i; oj = j > 191 ? 191 : j;
}

// ---------------------------------------------------------------------------
// All five fp32->bf16 conversions in ONE launch. Segment sizes in f32x4:
// Wc1 4194304 | W1 2097152 | W2 524288 | W3 131072 | f 196608  (sum 7143424)
// ---------------------------------------------------------------------------
#define CVT_N 7143424
__global__ __launch_bounds__(256)
void k_cvt_all(const float* __restrict__ s0, u16* __restrict__ d0,
               const float* __restrict__ s1, u16* __restrict__ d1,
               const float* __restrict__ s2, u16* __restrict__ d2,
               const float* __restrict__ s3, u16* __restrict__ d3,
               const float* __restrict__ s4, u16* __restrict__ d4)
{
    int i = blockIdx.x * 256 + threadIdx.x;
    if (i >= CVT_N) return;
    const float* s; u16* d; int j;
    if      (i < 4194304) { s = s0; d = d0; j = i; }
    else if (i < 6291456) { s = s1; d = d1; j = i - 4194304; }
    else if (i < 6815744) { s = s2; d = d2; j = i - 6291456; }
    else if (i < 6946816) { s = s3; d = d3; j = i - 6815744; }
    else                  { s = s4; d = d4; j = i - 6946816; }
    f32x4 v = ((const f32x4*)s)[j];
    ((uint2*)d)[j] = make_uint2(pkbf(v.x, v.y), pkbf(v.z, v.w));
}

// ---------------------------------------------------------------------------
// cam partials: camp[z][row][col] = (fb @ Wc1b^T) over k in [z*1024,(z+1)*1024)
// M=192,N=4096. BM=64,BN=128,BK=64, split-K=4 via blockIdx.z. grid (3,32,4).
// ---------------------------------------------------------------------------
__global__ __launch_bounds__(256, 2)
void k_cam(const u16* __restrict__ fb, const u16* __restrict__ Wc1b,
           float* __restrict__ camp)
{
    __shared__ __align__(16) u16 As[64 * 64];
    __shared__ __align__(16) u16 Bs[128 * 64];
    const int t = threadIdx.x, l = t & 63, w = t >> 6;
    const int m0 = blockIdx.x * 64, n0 = blockIdx.y * 128;
    const int kbeg = blockIdx.z * 1024, kend = kbeg + 1024;
    const int lr8 = l >> 3;
    const int lc8 = (l & 7) ^ lr8;
    const u16* Ab = fb   + (size_t)(m0 + w * 16 + lr8) * 4096 + lc8 * 8;
    const u16* Bb = Wc1b + (size_t)(n0 + w * 32 + lr8) * 4096 + lc8 * 8;
    f32x4 acc[2][4] = {};
    const int wr = (w >> 1) * 32, wc = (w & 1) * 64;
    const int lrow = l & 15, lq = l >> 4, s = lrow & 7;

    for (int k0 = kbeg; k0 < kend; k0 += 64) {
        __syncthreads();
#pragma unroll
        for (int q = 0; q < 2; ++q)
            gll16(&As[(w * 16 + q * 8) * 64], Ab + (size_t)q * 8 * 4096 + k0);
#pragma unroll
        for (int q = 0; q < 4; ++q)
            gll16(&Bs[(w * 32 + q * 8) * 64], Bb + (size_t)q * 8 * 4096 + k0);
        __syncthreads();
#pragma unroll
        for (int kk8 = 0; kk8 < 8; kk8 += 4) {
            const int co = ((kk8 + lq) ^ s) * 8;
            bf16x8 af[2], bfr[4];
#pragma unroll
            for (int mi = 0; mi < 2; ++mi)
                af[mi] = *(const bf16x8*)&As[(wr + mi * 16 + lrow) * 64 + co];
#pragma unroll
            for (int ni = 0; ni < 4; ++ni)
                bfr[ni] = *(const bf16x8*)&Bs[(wc + ni * 16 + lrow) * 64 + co];
#pragma unroll
            for (int mi = 0; mi < 2; ++mi)
#pragma unroll
                for (int ni = 0; ni < 4; ++ni)
                    acc[mi][ni] = MFMA16(af[mi], bfr[ni], acc[mi][ni]);
        }
    }
    float* cz = camp + (size_t)blockIdx.z * 192 * 4096;
    const int rq = (l >> 4) * 4;
#pragma unroll
    for (int ni = 0; ni < 4; ++ni) {
        const int col = n0 + wc + ni * 16 + lrow;
#pragma unroll
        for (int mi = 0; mi < 2; ++mi) {
            const int rbase = m0 + wr + mi * 16 + rq;
#pragma unroll
            for (int v = 0; v < 4; ++v)
                cz[(size_t)(rbase + v) * 4096 + col] = acc[mi][ni][v];
        }
    }
}

// ---------------------------------------------------------------------------
// g = f - relu(sum_z camp[z] + bc1). 196608 f32x4 groups, grid 768.
// ---------------------------------------------------------------------------
__global__ __launch_bounds__(256)
void k_gfin(const float* __restrict__ camp, const float* __restrict__ bc1,
            const float* __restrict__ f, float* __restrict__ g)
{
    const int i = blockIdx.x * 256 + threadIdx.x;       // < 196608
    const int col4 = (i * 4) & 4095;
    f32x4 p0 = ((const f32x4*)camp)[i];
    f32x4 p1 = ((const f32x4*)(camp + 786432))[i];
    f32x4 p2 = ((const f32x4*)(camp + 1572864))[i];
    f32x4 p3 = ((const f32x4*)(camp + 2359296))[i];
    f32x4 b = *(const f32x4*)(bc1 + col4);
    f32x4 fv = ((const f32x4*)f)[i];
    f32x4 r;
    r.x = fv.x - fmaxf(p0.x + p1.x + p2.x + p3.x + b.x, 0.0f);
    r.y = fv.y - fmaxf(p0.y + p1.y + p2.y + p3.y + b.y, 0.0f);
    r.z = fv.z - fmaxf(p0.z + p1.z + p2.z + p3.z + b.z, 0.0f);
    r.w = fv.w - fmaxf(p0.w + p1.w + p2.w + p3.w + b.w, 0.0f);
    ((f32x4*)g)[i] = r;
}

// ---------------------------------------------------------------------------
// dist[r, :] = bf16(|g_i - g_j|). One 16B chunk per thread. grid (2, rows).
// ---------------------------------------------------------------------------
__global__ __launch_bounds__(256)
void k_distgen(const float* __restrict__ g, u16* __restrict__ dist, int row0)
{
    const int r = blockIdx.y;
    const int c = blockIdx.x * 256 + threadIdx.x;       // chunk 0..511
    int pi, pj; tri_decode(row0 + r, pi, pj);
    const float* gi = g + (size_t)pi * 4096 + c * 8;
    const float* gj = g + (size_t)pj * 4096 + c * 8;
    f32x4 a0 = ((const f32x4*)gi)[0], a1 = ((const f32x4*)gi)[1];
    f32x4 b0 = ((const f32x4*)gj)[0], b1 = ((const f32x4*)gj)[1];
    uint4 o;
    o.x = pkbf(fabsf(b0.x - a0.x), fabsf(b0.y - a0.y));
    o.y = pkbf(fabsf(b0.z - a0.z), fabsf(b0.w - a0.w));
    o.z = pkbf(fabsf(b1.x - a1.x), fabsf(b1.y - a1.y));
    o.w = pkbf(fabsf(b1.z - a1.z), fabsf(b1.w - a1.w));
    *reinterpret_cast<uint4*>(dist + (size_t)r * 4096 + c * 8) = o;
}

// ---------------------------------------------------------------------------
// C = relu(A @ B^T + bias), bf16, 16x16x32 MFMA. BM=BN=128, BK=64, 256 thr,
// wave tile 64x64. grid (N/128, M/128): x = COLUMN tile (fast).
// XOR-swizzled LDS: stage chunk (l&7)^(l>>3), read chunk (ck)^(row&7).
// ---------------------------------------------------------------------------
__global__ __launch_bounds__(256, 2)
void k_gemm_relu(const u16* __restrict__ A, const u16* __restrict__ B,
                 const float* __restrict__ bias, u16* __restrict__ C,
                 int N, int K)
{
    __shared__ __align__(16) u16 As[128 * 64];
    __shared__ __align__(16) u16 Bs[128 * 64];
    const int t = threadIdx.x, l = t & 63, w = t >> 6;
    const int m0 = blockIdx.y * 128, n0 = blockIdx.x * 128;   // x = column!
    const int lr8 = l >> 3;
    const int lc8 = (l & 7) ^ lr8;
    const u16* Ab = A + (size_t)(m0 + w * 32 + lr8) * K + lc8 * 8;
    const u16* Bb = B + (size_t)(n0 + w * 32 + lr8) * K + lc8 * 8;
    f32x4 acc[4][4] = {};
    const int wr = (w >> 1) * 64, wc = (w & 1) * 64;
    const int lrow = l & 15, lq = l >> 4, s = lrow & 7;

    for (int k0 = 0; k0 < K; k0 += 64) {
        __syncthreads();
#pragma unroll
        for (int q = 0; q < 4; ++q) {
            gll16(&As[(w * 32 + q * 8) * 64], Ab + (size_t)q * 8 * K + k0);
            gll16(&Bs[(w * 32 + q * 8) * 64], Bb + (size_t)q * 8 * K + k0);
        }
        __syncthreads();
#pragma unroll
        for (int kk8 = 0; kk8 < 8; kk8 += 4) {
            const int co = ((kk8 + lq) ^ s) * 8;
            bf16x8 af[4], bfr[4];
#pragma unroll
            for (int mi = 0; mi < 4; ++mi)
                af[mi] = *(const bf16x8*)&As[(wr + mi * 16 + lrow) * 64 + co];
#pragma unroll
            for (int ni = 0; ni < 4; ++ni)
                bfr[ni] = *(const bf16x8*)&Bs[(wc + ni * 16 + lrow) * 64 + co];
#pragma unroll
            for (int mi = 0; mi < 4; ++mi)
#pragma unroll
                for (int ni = 0; ni < 4; ++ni)
                    acc[mi][ni] = MFMA16(af[mi], bfr[ni], acc[mi][ni]);
        }
    }
    const int rq = (l >> 4) * 4;
#pragma unroll
    for (int ni = 0; ni < 4; ++ni) {
        const int col = n0 + wc + ni * 16 + lrow;
        const float bv = bias[col];
#pragma unroll
        for (int mi = 0; mi < 4; ++mi) {
            const int rbase = m0 + wr + mi * 16 + rq;
#pragma unroll
            for (int v = 0; v < 4; ++v) {
                float x = fmaxf(acc[mi][ni][v] + bv, 0.0f);
                C[(size_t)(rbase + v) * N + col] = (u16)(pkbf(x, 0.0f) & 0xFFFF);
            }
        }
    }
}

// ---------------------------------------------------------------------------
// Fused L3+head: logit[r0+row] += sum_col relu(h2@W3^T + b3)[row,col]*Ws[col].
// Same GEMM core (N=512, K=1024, grid (4, rows/128)). Epilogue: per (mi,v)
// row-slot, dot partial over this lane's 4 cols, butterfly-reduce across the
// 16 lrow lanes (xor masks 1,2,4,8 stay within the l>>4 quad since row is
// determined by l>>4), one fp32 atomicAdd per row-slot from lane lrow==0.
// ---------------------------------------------------------------------------
__global__ __launch_bounds__(256, 2)
void k_gemm3(const u16* __restrict__ A, const u16* __restrict__ B,
             const float* __restrict__ bias, const float* __restrict__ Wsv,
             float* __restrict__ logit, int r0)
{
    const int N = 512, K = 1024;
    __shared__ __align__(16) u16 As[128 * 64];
    __shared__ __align__(16) u16 Bs[128 * 64];
    const int t = threadIdx.x, l = t & 63, w = t >> 6;
    const int m0 = blockIdx.y * 128, n0 = blockIdx.x * 128;
    const int lr8 = l >> 3;
    const int lc8 = (l & 7) ^ lr8;
    const u16* Ab = A + (size_t)(m0 + w * 32 + lr8) * K + lc8 * 8;
    const u16* Bb = B + (size_t)(n0 + w * 32 + lr8) * K + lc8 * 8;
    f32x4 acc[4][4] = {};
    const int wr = (w >> 1) * 64, wc = (w & 1) * 64;
    const int lrow = l & 15, lq = l >> 4, s = lrow & 7;

    for (int k0 = 0; k0 < K; k0 += 64) {
        __syncthreads();
#pragma unroll
        for (int q = 0; q < 4; ++q) {
            gll16(&As[(w * 32 + q * 8) * 64], Ab + (size_t)q * 8 * K + k0);
            gll16(&Bs[(w * 32 + q * 8) * 64], Bb + (size_t)q * 8 * K + k0);
        }
        __syncthreads();
#pragma unroll
        for (int kk8 = 0; kk8 < 8; kk8 += 4) {
            const int co = ((kk8 + lq) ^ s) * 8;
            bf16x8 af[4], bfr[4];
#pragma unroll
            for (int mi = 0; mi < 4; ++mi)
                af[mi] = *(const bf16x8*)&As[(wr + mi * 16 + lrow) * 64 + co];
#pragma unroll
            for (int ni = 0; ni < 4; ++ni)
                bfr[ni] = *(const bf16x8*)&Bs[(wc + ni * 16 + lrow) * 64 + co];
#pragma unroll
            for (int mi = 0; mi < 4; ++mi)
#pragma unroll
                for (int ni = 0; ni < 4; ++ni)
                    acc[mi][ni] = MFMA16(af[mi], bfr[ni], acc[mi][ni]);
        }
    }
    const int rq = (l >> 4) * 4;
    float wv[4], bv[4];
#pragma unroll
    for (int ni = 0; ni < 4; ++ni) {
        const int col = n0 + wc + ni * 16 + lrow;
        wv[ni] = Wsv[col];
        bv[ni] = bias[col];
    }
#pragma unroll
    for (int mi = 0; mi < 4; ++mi) {
#pragma unroll
        for (int v = 0; v < 4; ++v) {
            float p = 0.0f;
#pragma unroll
            for (int ni = 0; ni < 4; ++ni)
                p += fmaxf(acc[mi][ni][v] + bv[ni], 0.0f) * wv[ni];
            p += __shfl_xor(p, 1, 64);
            p += __shfl_xor(p, 2, 64);
            p += __shfl_xor(p, 4, 64);
            p += __shfl_xor(p, 8, 64);
            if (lrow == 0)
                atomicAdd(&logit[r0 + m0 + wr + mi * 16 + rq + v], p);
        }
    }
}

// ---------------------------------------------------------------------------
// out[i,j] = out[j,i] = sigmoid(logit[r] + bs). One thread per tri-row.
// ---------------------------------------------------------------------------
__global__ __launch_bounds__(256)
void k_sig(const float* __restrict__ logit, const float* __restrict__ bsv,
           float* __restrict__ out)
{
    const int r = blockIdx.x * 256 + threadIdx.x;
    if (r >= TRI) return;
    int pi, pj; tri_decode(r, pi, pj);
    float v = 1.0f / (1.0f + __expf(-(logit[r] + bsv[0])));
    out[pi * NTRK + pj] = v;
    out[pj * NTRK + pi] = v;
}

// ---------------------------------------------------------------------------
extern "C" void kernel_launch(void* const* d_in, const int* in_sizes, int n_in,
                              void* d_out, int out_size, void* d_ws, size_t ws_size,
                              hipStream_t stream)
{
    const float* f   = (const float*)d_in[0];
    const float* Wc1 = (const float*)d_in[1];
    const float* bc1 = (const float*)d_in[2];
    const float* W1  = (const float*)d_in[3];
    const float* b1  = (const float*)d_in[4];
    const float* W2  = (const float*)d_in[5];
    const float* b2  = (const float*)d_in[6];
    const float* W3  = (const float*)d_in[7];
    const float* b3  = (const float*)d_in[8];
    const float* Wsv = (const float*)d_in[9];
    const float* bsv = (const float*)d_in[10];
    float* out = (float*)d_out;

    // ---- workspace layout ----
    // persistent: W1b 16M | W2b 4M | W3b 1M | fb 1.5M | g 3M | logit 75K
    // overlay region at chunkbase:
    //   phase A: Wc1b (32M) + camp (12M)   [dead before chunk loop]
    //   phase B: dist (8192R) + h1 (4096R); h2 (2048R) overlays dist.
    char* wsb = (char*)d_ws;
    size_t off = 0;
    u16*   W1b   = (u16*)(wsb + off);  off += (size_t)2048 * 4096 * 2;
    u16*   W2b   = (u16*)(wsb + off);  off += (size_t)1024 * 2048 * 2;
    u16*   W3b   = (u16*)(wsb + off);  off += (size_t)512  * 1024 * 2;
    u16*   fb    = (u16*)(wsb + off);  off += (size_t)192  * 4096 * 2;
    float* g     = (float*)(wsb + off); off += (size_t)192 * 4096 * 4;
    float* logit = (float*)(wsb + off); off += (size_t)TRIP * 4;
    const size_t chunkbase = off;
    u16*   Wc1b = (u16*)(wsb + chunkbase);
    float* camp = (float*)(wsb + chunkbase + (size_t)4096 * 4096 * 2);
    const size_t phaseA = (size_t)4096 * 4096 * 2 + (size_t)4 * 192 * 4096 * 4;

    // measured-best asymmetric ladder (round-9).
    const int Rcand[6] = {18688, 14336, 9344, 4736, 2432, 1280};
    int R = 128;
    for (int c = 0; c < 6; ++c) {
        size_t chunk = (size_t)Rcand[c] * 12288;
        if (chunk < phaseA) chunk = phaseA;
        if (chunkbase + chunk <= ws_size) { R = Rcand[c]; break; }
    }
    u16* dist = (u16*)(wsb + chunkbase);
    u16* h1 = dist + (size_t)R * 4096;
    u16* h2 = dist;                       // overlays dist (dead after L1)

    hipMemsetAsync(logit, 0, (size_t)TRIP * 4, stream);
    k_cvt_all<<<(CVT_N + 255) / 256, 256, 0, stream>>>(
        Wc1, Wc1b, W1, W1b, W2, W2b, W3, W3b, f, fb);
    k_cam<<<dim3(3, 32, 4), 256, 0, stream>>>(fb, Wc1b, camp);
    k_gfin<<<768, 256, 0, stream>>>(camp, bc1, f, g);

    for (int r0 = 0; r0 < TRI; r0 += R) {
        int rows = TRIP - r0; if (rows > R) rows = R;   // mult of 128
        k_distgen<<<dim3(2, rows), 256, 0, stream>>>(g, dist, r0);
        k_gemm_relu<<<dim3(16, rows / 128), 256, 0, stream>>>(dist, W1b, b1, h1, 2048, 4096);
        k_gemm_relu<<<dim3(8,  rows / 128), 256, 0, stream>>>(h1, W2b, b2, h2, 1024, 2048);
        k_gemm3<<<dim3(4, rows / 128), 256, 0, stream>>>(h2, W3b, b3, Wsv, logit, r0);
    }
    k_sig<<<(TRI + 255) / 256, 256, 0, stream>>>(logit, bsv, out);
}